// Round 9
// baseline (365.488 us; speedup 1.0000x reference)
//
#include <hip/hip_runtime.h>
#include <math.h>

typedef unsigned short u16;
typedef __attribute__((ext_vector_type(8))) short bf16x8;
typedef __attribute__((ext_vector_type(4))) float f32x4;
typedef __attribute__((ext_vector_type(4))) unsigned int u32x4;

#define B_ 2
#define S_ 2048
#define D_ 1024
#define H_ 16
#define DK_ 64
#define DFF_ 4096
#define EPS_ 1.1920928955078125e-07f
// (1/sqrt(64)) * log2(e)
#define EXP2SC 0.18033688011112042f

__device__ __forceinline__ float bf2f(u16 u) {
  unsigned int v = ((unsigned int)u) << 16;
  return __builtin_bit_cast(float, v);
}
__device__ __forceinline__ u16 f2bf(float f) {
  unsigned int x = __builtin_bit_cast(unsigned int, f);
  x += 0x7fffu + ((x >> 16) & 1u);   // RNE
  return (u16)(x >> 16);
}

// raw v_exp_f32 (scores bounded ~+-6: no denormal/range fixup needed; the
// default exp2f expansion is ~6 insts of OCML guard code -- pure VALU waste)
#if __has_builtin(__builtin_amdgcn_exp2f)
__device__ __forceinline__ float exp2r(float x) { return __builtin_amdgcn_exp2f(x); }
#else
__device__ __forceinline__ float exp2r(float x) { return exp2f(x); }
#endif

typedef __attribute__((address_space(3))) unsigned int lds_uint;
typedef const __attribute__((address_space(1))) unsigned int glb_uint;
__device__ __forceinline__ void gload16(const void* g, void* l) {
  __builtin_amdgcn_global_load_lds((glb_uint*)g, (lds_uint*)l, 16, 0, 0);
}

// counted vmcnt wait (T4): literal immediate via if constexpr dispatch
template <int N>
__device__ __forceinline__ void waitcnt_vm() {
  if constexpr (N == 8) asm volatile("s_waitcnt vmcnt(8)" ::: "memory");
  else if constexpr (N == 6) asm volatile("s_waitcnt vmcnt(6)" ::: "memory");
  else if constexpr (N == 4) asm volatile("s_waitcnt vmcnt(4)" ::: "memory");
  else if constexpr (N == 3) asm volatile("s_waitcnt vmcnt(3)" ::: "memory");
  else asm volatile("s_waitcnt vmcnt(0)" ::: "memory");
}

// pack two f32 -> one dword of 2 bf16 (lo = first arg)
__device__ __forceinline__ unsigned int cvtpk(float lo, float hi) {
  unsigned int d;
  asm("v_cvt_pk_bf16_f32 %0, %1, %2" : "=v"(d) : "v"(lo), "v"(hi));
  return d;
}
// swap a's upper 32 lanes with b's lower 32 lanes
__device__ __forceinline__ void plswap32(unsigned int& a, unsigned int& b) {
  asm("v_permlane32_swap_b32 %0, %1" : "+v"(a), "+v"(b));
}
// swap a's odd 16-lane rows with b's even 16-lane rows
__device__ __forceinline__ void plswap16(unsigned int& a, unsigned int& b) {
  asm("v_permlane16_swap_b32 %0, %1" : "+v"(a), "+v"(b));
}

// XCD-chunked bijective blockIdx swizzle (T1, m157): consecutive remapped ids
// share the same m-panel AND the same XCD L2. Requires gridDim.x*gridDim.y % 8 == 0.
__device__ __forceinline__ void xcd_swizzle(int& bx, int& by) {
  const int nx = gridDim.x;
  const int nwg = nx * gridDim.y;
  const int lin = blockIdx.y * nx + blockIdx.x;
  const int swz = (lin & 7) * (nwg >> 3) + (lin >> 3);
  bx = swz % nx;
  by = swz / nx;
}

// 3D variant, z FASTEST in work order: all z-slices of one (x,y) output tile
// are consecutive work items -> same XCD -> split-K atomic RMWs stay in ONE
// L2 (R5's z=4 regression is attributed to cross-XCD atomic contention).
__device__ __forceinline__ void xcd_swizzle3(int& bx, int& by, int& bz) {
  const int gx = gridDim.x, gy = gridDim.y, gz = gridDim.z;
  const int nb = gx * gy * gz;
  const int lin = ((int)blockIdx.z * gy + blockIdx.y) * gx + blockIdx.x;
  const int w = (lin & 7) * (nb >> 3) + (lin >> 3);
  bz = w % gz;
  const int r = w / gz;
  bx = r % gx;
  by = r / gx;
}

// ---------- fused prep 1: 4x DxD transpose+convert (wq,wk,wv,wo) + RoPE table ----------
__global__ __launch_bounds__(256) void prep_qkvo(
    const float* __restrict__ wq, const float* __restrict__ wk,
    const float* __restrict__ wv, const float* __restrict__ wo,
    u16* __restrict__ qkvT, u16* __restrict__ woT,
    float* __restrict__ cosT, float* __restrict__ sinT) {
  __shared__ float t[32][33];
  const int bid = blockIdx.x;
  const int tid = threadIdx.x;
  if (bid < 4096) {
    const int m = bid >> 10;      // 0..3: wq,wk,wv,wo
    const int tb = bid & 1023;    // 32x32 tile id
    const float* src = (m == 0) ? wq : (m == 1) ? wk : (m == 2) ? wv : wo;
    u16* dst = (m == 3) ? woT : qkvT + (size_t)m * D_ * D_;
    const int c0 = (tb & 31) * 32, r0 = (tb >> 5) * 32;
    const int tx = tid & 31, ty = tid >> 5;
#pragma unroll
    for (int i = 0; i < 32; i += 8)
      t[ty + i][tx] = src[(size_t)(r0 + ty + i) * D_ + (c0 + tx)];
    __syncthreads();
#pragma unroll
    for (int i = 0; i < 32; i += 8)
      dst[(size_t)(c0 + ty + i) * D_ + (r0 + tx)] = f2bf(t[tx][ty + i]);
  } else {
    const int idx = (bid - 4096) * 256 + tid;  // S_*32 = 65536 entries
    const int s = idx >> 5, i = idx & 31;
    double inv = exp(((double)(-2 * i) / (double)DK_) * log(10000.0));
    double ang = (double)s * inv;
    cosT[idx] = (float)cos(ang);
    sinT[idx] = (float)sin(ang);
  }
}

// ---------- fused prep 2: w1 (DxDFF) and w2 (DFFxD) transpose+convert ----------
__global__ __launch_bounds__(256) void prep_w12(
    const float* __restrict__ w1, const float* __restrict__ w2,
    u16* __restrict__ w1T, u16* __restrict__ w2T) {
  __shared__ float t[32][33];
  const int bid = blockIdx.x;
  const int tid = threadIdx.x;
  const int tx = tid & 31, ty = tid >> 5;
  if (bid < 4096) {
    // w1: R=D_, C=DFF_; tiles: 128 (C) x 32 (R)
    const int c0 = (bid & 127) * 32, r0 = (bid >> 7) * 32;
#pragma unroll
    for (int i = 0; i < 32; i += 8)
      t[ty + i][tx] = w1[(size_t)(r0 + ty + i) * DFF_ + (c0 + tx)];
    __syncthreads();
#pragma unroll
    for (int i = 0; i < 32; i += 8)
      w1T[(size_t)(c0 + ty + i) * D_ + (r0 + tx)] = f2bf(t[tx][ty + i]);
  } else {
    // w2: R=DFF_, C=D_; tiles: 32 (C) x 128 (R)
    const int b2 = bid - 4096;
    const int c0 = (b2 & 31) * 32, r0 = (b2 >> 5) * 32;
#pragma unroll
    for (int i = 0; i < 32; i += 8)
      t[ty + i][tx] = w2[(size_t)(r0 + ty + i) * D_ + (c0 + tx)];
    __syncthreads();
#pragma unroll
    for (int i = 0; i < 32; i += 8)
      w2T[(size_t)(c0 + ty + i) * DFF_ + (r0 + tx)] = f2bf(t[tx][ty + i]);
  }
}

// ---------- RMSNorm: fp32 in, bf16 out ----------
__global__ __launch_bounds__(256) void rmsnorm_k(const float* __restrict__ X,
                                                 const float* __restrict__ g,
                                                 u16* __restrict__ out) {
  const int row = blockIdx.x;
  const float* xr = X + (size_t)row * D_;
  u16* orow = out + (size_t)row * D_;
  const int tid = threadIdx.x;
  float vals[4];
  float s = 0.f;
#pragma unroll
  for (int j = 0; j < 4; j++) {
    float v = xr[tid + j * 256];
    vals[j] = v;
    s += v * v;
  }
#pragma unroll
  for (int off = 32; off > 0; off >>= 1) s += __shfl_down(s, off, 64);
  __shared__ float red[4];
  __shared__ float ssc;
  int lane = tid & 63, wave = tid >> 6;
  if (lane == 0) red[wave] = s;
  __syncthreads();
  if (tid == 0) ssc = 1.0f / sqrtf((red[0] + red[1] + red[2] + red[3]) * (1.0f / D_) + EPS_);
  __syncthreads();
  float sc = ssc;
#pragma unroll
  for (int j = 0; j < 4; j++) {
    int i = tid + j * 256;
    orow[i] = f2bf(vals[j] * sc * g[i]);
  }
}

// ===== K-loop v4: BK=32 double-buffer + counted vmcnt (T4) =====
// Half the LDS of v3 (2 x BK=32 buffers): 128^2 tile = 32 KB -> 4 blocks/CU
// capacity -- the flash-v5 recipe (schedule + TLP) applied to the GEMMs.
// Per stage, each wave issues L = WR/2 + WC/2 gloads; steady state has 2
// stages (2L) in flight; vmcnt(L) retires only the older one, so the newer
// stage crosses both barriers with a full compute phase + other-block waves
// to hide its latency.
#define GK_STAGE(BU, K0)                                                               \
  _Pragma("unroll")                                                                    \
  for (int c = wave; c < BM / 16; c += 4) {                                            \
    const u16* gp = gkA + (size_t)(m0 + c * 16 + lrow) * gkLD + (K0) + lcol;           \
    gload16(gp, (char*)As + __builtin_amdgcn_readfirstlane((BU) * (BM * 64) + c * 1024)); \
  }                                                                                    \
  _Pragma("unroll")                                                                    \
  for (int c = wave; c < BN / 16; c += 4) {                                            \
    const u16* gp = gkB + (size_t)(n0 + c * 16 + lrow) * gkLD + (K0) + lcol;           \
    gload16(gp, (char*)Bs + __builtin_amdgcn_readfirstlane((BU) * (BN * 64) + c * 1024)); \
  }

#define GK_COMPUTE(BU)                                                                 \
  {                                                                                    \
    bf16x8 af[WR], bfv[WC];                                                            \
    _Pragma("unroll")                                                                  \
    for (int i = 0; i < WR; i++)                                                       \
      af[i] = *(const bf16x8*)&As[(BU) * (BM * 32) + (wm + i * 16 + l16) * 32 + quad * 8]; \
    _Pragma("unroll")                                                                  \
    for (int j = 0; j < WC; j++)                                                       \
      bfv[j] = *(const bf16x8*)&Bs[(BU) * (BN * 32) + (wn + j * 16 + l16) * 32 + quad * 8]; \
    _Pragma("unroll")                                                                  \
    for (int i = 0; i < WR; i++)                                                       \
      _Pragma("unroll")                                                                \
      for (int j = 0; j < WC; j++)                                                     \
        acc[i][j] = __builtin_amdgcn_mfma_f32_16x16x32_bf16(af[i], bfv[j], acc[i][j], 0, 0, 0); \
  }

#define GEMM_KLOOP(APTR, BPTR, KLEN, KLD)                                              \
  {                                                                                    \
    const u16* gkA = (APTR);                                                           \
    const u16* gkB = (BPTR);                                                           \
    const int gkLD = (KLD);                                                            \
    GK_STAGE(0, 0)                                                                     \
    GK_STAGE(1, 32)                                                                    \
    int gkcur = 0;                                                                     \
    for (int k0 = 0; k0 < (KLEN); k0 += 32) {                                          \
      if (k0 + 32 < (KLEN)) waitcnt_vm<WR / 2 + WC / 2>();  /* older stage only */     \
      else waitcnt_vm<0>();                                 /* last tile: drain */     \
      __builtin_amdgcn_s_barrier();                                                    \
      GK_COMPUTE(gkcur)                                                                \
      __builtin_amdgcn_s_barrier();                         /* reads of buf done */    \
      if (k0 + 64 < (KLEN)) { GK_STAGE(gkcur, k0 + 64) }                               \
      gkcur ^= 1;                                                                      \
    }                                                                                  \
  }

// ---------- generic GEMM: MODE 0 bf16, MODE 1 relu->bf16, MODE 2 fp32 = v + resF ----------
template <int MODE, int WR, int WC>
__global__ __launch_bounds__(256, 4) void gemm_bt(
    const u16* __restrict__ A, const u16* __restrict__ Bt, const float* __restrict__ bias,
    u16* __restrict__ outB, float* __restrict__ outF, const float* __restrict__ resF,
    int M, int N, int K) {
  constexpr int BM = 2 * WR * 16;
  constexpr int BN = 2 * WC * 16;
  __shared__ u16 As[2 * BM * 32];
  __shared__ u16 Bs[2 * BN * 32];
  const int tid = threadIdx.x;
  const int wave = tid >> 6, lane = tid & 63, quad = lane >> 4, l16 = lane & 15;
  const int wm = (wave >> 1) * (WR * 16), wn = (wave & 1) * (WC * 16);
  int bx, by;
  xcd_swizzle(bx, by);
  const int m0 = by * BM, n0 = bx * BN;
  const int lrow = lane >> 2, lcol = (lane & 3) * 8;
  f32x4 acc[WR][WC] = {};
  GEMM_KLOOP(A, Bt, K, K)
#pragma unroll
  for (int i = 0; i < WR; i++)
#pragma unroll
    for (int j = 0; j < WC; j++) {
      int col = n0 + wn + j * 16 + l16;
      float bv = bias[col];
#pragma unroll
      for (int r = 0; r < 4; r++) {
        int row = m0 + wm + i * 16 + quad * 4 + r;
        size_t off = (size_t)row * N + col;
        float v = acc[i][j][r] + bv;
        if constexpr (MODE == 1) v = fmaxf(v, 0.f);
        if constexpr (MODE == 2) outF[off] = v + resF[off];
        else outB[off] = f2bf(v);
      }
    }
}

// ---------- fused QKV GEMM + RoPE (table-based): Bt = [wqT;wkT;wvT] ----------
// Q is additionally pre-scaled by EXP2SC (softmax exp2 scale folded in; Q buf
// is consumed only by flash_attn).
__global__ __launch_bounds__(256, 4) void gemm_qkv(
    const u16* __restrict__ A, const u16* __restrict__ Bt,
    const float* __restrict__ bq, const float* __restrict__ bk, const float* __restrict__ bv,
    const float* __restrict__ cosT, const float* __restrict__ sinT,
    u16* __restrict__ Qb, u16* __restrict__ Kb, u16* __restrict__ VT, int M, int K) {
  constexpr int WR = 4, WC = 4;
  constexpr int BM = 128, BN = 128;
  __shared__ u16 As[2 * BM * 32];
  __shared__ u16 Bs[2 * BN * 32];
  const int tid = threadIdx.x;
  const int wave = tid >> 6, lane = tid & 63, quad = lane >> 4, l16 = lane & 15;
  const int wm = (wave >> 1) * 64, wn = (wave & 1) * 64;
  int bx, by;
  xcd_swizzle(bx, by);
  const int m0 = by * BM, n0 = bx * BN;
  const int lrow = lane >> 2, lcol = (lane & 3) * 8;
  f32x4 acc[WR][WC] = {};
  GEMM_KLOOP(A, Bt, K, K)
  const int g = n0 >> 10;  // whole tile is one of Q/K/V (BN=128 divides 1024)
  if (g < 2) {
    // Q or K with fused RoPE via table. Pair (jp, jp+2): cols c0 and c0+32 (same head).
    u16* dst = (g == 0) ? Qb : Kb;
    const float* bias = (g == 0) ? bq : bk;
    const float scq = (g == 0) ? EXP2SC : 1.0f;
#pragma unroll
    for (int i = 0; i < WR; i++)
#pragma unroll
      for (int jp = 0; jp < 2; jp++) {
        int col0 = n0 + wn + jp * 16 + l16;
        int c0 = col0 & 1023;               // dk = c0&63 in [0,32)
        float bv0 = bias[c0], bv1 = bias[c0 + 32];
        int irot = jp * 16 + l16;           // rotation index (0..31)
        int row0 = m0 + wm + i * 16 + quad * 4;
#pragma unroll
        for (int r = 0; r < 4; r++) {
          int row = row0 + r;
          int s2 = row & 2047;
          float cs = cosT[s2 * 32 + irot];
          float sn = sinT[s2 * 32 + irot];
          float x0 = acc[i][jp][r] + bv0;
          float x1 = acc[i][jp + 2][r] + bv1;
          dst[(size_t)row * D_ + c0]      = f2bf((x0 * cs - x1 * sn) * scq);
          dst[(size_t)row * D_ + c0 + 32] = f2bf((x1 * cs + x0 * sn) * scq);
        }
      }
  } else {
#pragma unroll
    for (int i = 0; i < WR; i++)
#pragma unroll
      for (int j = 0; j < WC; j++) {
        int col = n0 + wn + j * 16 + l16;
        int c = col & 1023;
        float bvv = bv[c];
        int row0 = m0 + wm + i * 16 + quad * 4;
        int hh = c >> 6, dk = c & 63;
        int b = row0 >> 11, s2 = row0 & 2047;
        ushort4 pv;
        pv.x = f2bf(acc[i][j][0] + bvv);
        pv.y = f2bf(acc[i][j][1] + bvv);
        pv.z = f2bf(acc[i][j][2] + bvv);
        pv.w = f2bf(acc[i][j][3] + bvv);
        *(ushort4*)&VT[(((size_t)(b * H_ + hh)) * DK_ + dk) * S_ + s2] = pv;
      }
  }
}

// ---------- split-K GEMM, fp32 atomic-add epilogue (residual pre-loaded in outF) ----------
template <int WR, int WC>
__global__ __launch_bounds__(256, 4) void gemm_splitk(
    const u16* __restrict__ A, const u16* __restrict__ Bt, const float* __restrict__ bias,
    float* outF, int M, int N, int Kslice, int Kld) {
  constexpr int BM = 2 * WR * 16;
  constexpr int BN = 2 * WC * 16;
  __shared__ u16 As[2 * BM * 32];
  __shared__ u16 Bs[2 * BN * 32];
  const int tid = threadIdx.x;
  const int wave = tid >> 6, lane = tid & 63, quad = lane >> 4, l16 = lane & 15;
  const int wm = (wave >> 1) * (WR * 16), wn = (wave & 1) * (WC * 16);
  int bx, by, bz;
  xcd_swizzle3(bx, by, bz);
  const int m0 = by * BM, n0 = bx * BN;
  const int lrow = lane >> 2, lcol = (lane & 3) * 8;
  const u16* Ao = A + (size_t)bz * Kslice;
  const u16* Bo = Bt + (size_t)bz * Kslice;
  f32x4 acc[WR][WC] = {};
  GEMM_KLOOP(Ao, Bo, Kslice, Kld)
  const bool addb = (bz == 0);
#pragma unroll
  for (int i = 0; i < WR; i++)
#pragma unroll
    for (int j = 0; j < WC; j++) {
      int col = n0 + wn + j * 16 + l16;
      float bv = addb ? bias[col] : 0.f;
#pragma unroll
      for (int r = 0; r < 4; r++) {
        int row = m0 + wm + i * 16 + quad * 4 + r;
        unsafeAtomicAdd(&outF[(size_t)row * N + col], acc[i][j][r] + bv);
      }
    }
}

// ---------- flash attention v5 ----------
// 128 q-rows/block (4 waves x 32 q), 64-key tiles double-buffered with the
// T4 counted-vmcnt schedule. 32KB LDS -> 4 blocks/CU = 4 waves/SIMD.
// Swapped QK^T; P in-register (cvt_pk + permlane); raw v_exp_f32 (exp2r);
// softmax denominator via MFMA ones-trick.
__device__ __forceinline__ void softmax_pack(f32x4 s0, f32x4 s1, f32x4 s2, f32x4 s3,
                                             bf16x8& pf0, bf16x8& pf1) {
  f32x4 p0, p1, p2, p3;
#pragma unroll
  for (int r = 0; r < 4; r++) {
    p0[r] = exp2r(s0[r]);
    p1[r] = exp2r(s1[r]);
    p2[r] = exp2r(s2[r]);
    p3[r] = exp2r(s3[r]);
  }
  unsigned int X0 = cvtpk(p0[0], p0[1]), X1 = cvtpk(p0[2], p0[3]);
  unsigned int Y0 = cvtpk(p1[0], p1[1]), Y1 = cvtpk(p1[2], p1[3]);
  unsigned int Z0 = cvtpk(p2[0], p2[1]), Z1 = cvtpk(p2[2], p2[3]);
  unsigned int W0 = cvtpk(p3[0], p3[1]), W1 = cvtpk(p3[2], p3[3]);
  // redistribute: after (swap32; swap16), first reg = dword j, second = dword j+2
  plswap32(X0, Y0); plswap16(X0, Y0);
  plswap32(X1, Y1); plswap16(X1, Y1);
  plswap32(Z0, W0); plswap16(Z0, W0);
  plswap32(Z1, W1); plswap16(Z1, W1);
  u32x4 lo = {X0, X1, Y0, Y1};
  u32x4 hi = {Z0, Z1, W0, W1};
  pf0 = __builtin_bit_cast(bf16x8, lo);
  pf1 = __builtin_bit_cast(bf16x8, hi);
}

__global__ __launch_bounds__(256, 4) void flash_attn(u16* __restrict__ Q,
                                                     const u16* __restrict__ Kg,
                                                     const u16* __restrict__ VT) {
  const int bh = blockIdx.y;
  const int b = bh >> 4, h = bh & 15;
  const int q0 = blockIdx.x * 128;
  const int tid = threadIdx.x;
  const int wave = tid >> 6, lane = tid & 63, quad = lane >> 4, l16 = lane & 15;
  const size_t base = (size_t)b * S_ * D_ + h * DK_;
  const size_t vbase = (size_t)bh * DK_ * S_;

  __shared__ u16 Ks[2][4096];   // per buf [64key][64dk]: byte = key*128 + (colb ^ ((key&7)<<4))
  __shared__ u16 Vts[2][4096];  // per buf [64dk][64key]: byte = dk*128  + (colb ^ ((dk&7)<<4))

  // staging: wave w covers rows w*16..w*16+15 (8 lanes/row, 2 gloads of 8 rows)
  const int srow8 = lane >> 3;                        // 0..7
  const int scol = ((lane & 7) ^ srow8) * 8;          // pre-swizzled u16 col
  const int kkey = wave * 16 + srow8;                 // +c*8 ; kkey&7 == srow8
  const u16* kp0 = Kg + base + (size_t)kkey * D_ + scol;
  const int vdk = wave * 16 + srow8;                  // +c*8 ; vdk&7 == srow8
  const u16* vp0 = VT + vbase + (size_t)vdk * S_ + scol;

#define FA_STAGE(BU, KT)                                                               \
  _Pragma("unroll")                                                                    \
  for (int c = 0; c < 2; c++) {                                                        \
    gload16(kp0 + (size_t)((KT) + c * 8) * D_,                                         \
            (char*)Ks + __builtin_amdgcn_readfirstlane((BU) * 8192 + wave * 2048 + c * 1024)); \
    gload16(vp0 + (size_t)(c * 8) * S_ + (KT),                                         \
            (char*)Vts + __builtin_amdgcn_readfirstlane((BU) * 8192 + wave * 2048 + c * 1024)); \
  }

  FA_STAGE(0, 0)
  FA_STAGE(1, 64)

  // Q fragments: qset a = rows wave*32+l16, qset b = +16; cols quad*8 (+32)
  const size_t qoffA = base + (size_t)(q0 + wave * 32 + l16) * D_ + quad * 8;
  const size_t qoffB = qoffA + (size_t)16 * D_;
  bf16x8 qa0 = *(const bf16x8*)(Q + qoffA);
  bf16x8 qa1 = *(const bf16x8*)(Q + qoffA + 32);
  bf16x8 qb0 = *(const bf16x8*)(Q + qoffB);
  bf16x8 qb1 = *(const bf16x8*)(Q + qoffB + 32);

  f32x4 oa[4] = {}, ob[4] = {};
  f32x4 lsa_acc = {}, lsb_acc = {};
  const u32x4 onesu = {0x3F803F80u, 0x3F803F80u, 0x3F803F80u, 0x3F803F80u};
  const bf16x8 ones = __builtin_bit_cast(bf16x8, onesu);
  const int sw = (l16 & 7) << 4;

#define FA_TILE(BU)                                                                    \
  {                                                                                    \
    const char* KsB = (const char*)Ks + (BU) * 8192;                                   \
    const char* VtsB = (const char*)Vts + (BU) * 8192;                                 \
    f32x4 sa[4] = {}, sb[4] = {};                                                      \
    __builtin_amdgcn_s_setprio(1);                                                     \
    _Pragma("unroll")                                                                  \
    for (int nt = 0; nt < 4; nt++) {                                                   \
      const char* krow = KsB + (nt * 16 + l16) * 128;                                  \
      bf16x8 k0 = *(const bf16x8*)(krow + ((quad * 16) ^ sw));                         \
      bf16x8 k1 = *(const bf16x8*)(krow + ((64 + quad * 16) ^ sw));                    \
      sa[nt] = __builtin_amdgcn_mfma_f32_16x16x32_bf16(k0, qa0, sa[nt], 0, 0, 0);      \
      sa[nt] = __builtin_amdgcn_mfma_f32_16x16x32_bf16(k1, qa1, sa[nt], 0, 0, 0);      \
      sb[nt] = __builtin_amdgcn_mfma_f32_16x16x32_bf16(k0, qb0, sb[nt], 0, 0, 0);      \
      sb[nt] = __builtin_amdgcn_mfma_f32_16x16x32_bf16(k1, qb1, sb[nt], 0, 0, 0);      \
    }                                                                                  \
    __builtin_amdgcn_s_setprio(0);                                                     \
    bf16x8 pa0, pa1, pb0, pb1;                                                         \
    softmax_pack(sa[0], sa[1], sa[2], sa[3], pa0, pa1);                                \
    softmax_pack(sb[0], sb[1], sb[2], sb[3], pb0, pb1);                                \
    __builtin_amdgcn_s_setprio(1);                                                     \
    lsa_acc = __builtin_amdgcn_mfma_f32_16x16x32_bf16(pa0, ones, lsa_acc, 0, 0, 0);    \
    lsa_acc = __builtin_amdgcn_mfma_f32_16x16x32_bf16(pa1, ones, lsa_acc, 0, 0, 0);    \
    lsb_acc = __builtin_amdgcn_mfma_f32_16x16x32_bf16(pb0, ones, lsb_acc, 0, 0, 0);    \
    lsb_acc = __builtin_amdgcn_mfma_f32_16x16x32_bf16(pb1, ones, lsb_acc, 0, 0, 0);    \
    _Pragma("unroll")                                                                  \
    for (int nt = 0; nt < 4; nt++) {                                                   \
      const char* vrow = VtsB + (nt * 16 + l16) * 128;                                 \
      bf16x8 v0 = *(const bf16x8*)(vrow + ((quad * 16) ^ sw));                         \
      bf16x8 v1 = *(const bf16x8*)(vrow + ((64 + quad * 16) ^ sw));                    \
      oa[nt] = __builtin_amdgcn_mfma_f32_16x16x32_bf16(pa0, v0, oa[nt], 0, 0, 0);      \
      oa[nt] = __builtin_amdgcn_mfma_f32_16x16x32_bf16(pa1, v1, oa[nt], 0, 0, 0);      \
      ob[nt] = __builtin_amdgcn_mfma_f32_16x16x32_bf16(pb0, v0, ob[nt], 0, 0, 0);      \
      ob[nt] = __builtin_amdgcn_mfma_f32_16x16x32_bf16(pb1, v1, ob[nt], 0, 0, 0);      \
    }                                                                                  \
    __builtin_amdgcn_s_setprio(0);                                                     \
  }

  // T4 schedule: vmcnt(4) retires only the older stage; the newer one stays
  // in flight across both barriers, hidden under a full tile of MFMA+VALU.
  int cur = 0;
  for (int kt = 0; kt < S_; kt += 64) {
    if (kt + 64 < S_) waitcnt_vm<4>();
    else waitcnt_vm<0>();
    __builtin_amdgcn_s_barrier();
    FA_TILE(cur)
    __builtin_amdgcn_s_barrier();
    if (kt + 128 < S_) { FA_STAGE(cur, kt + 128) }
    cur ^= 1;
  }
#undef FA_STAGE
#undef FA_TILE

  // lsX_acc[r] holds sum_k P[q][k] for q = quad*4+r on every l16 lane --
  // exactly the rows oa/ob[nt][r] cover; no cross-lane reduction needed.
#pragma unroll
  for (int r = 0; r < 4; r++) {
    float inva = 1.0f / lsa_acc[r];
    float invb = 1.0f / lsb_acc[r];
    const size_t aoff = base + (size_t)(q0 + wave * 32 + quad * 4 + r) * D_;
    const size_t boff = aoff + (size_t)16 * D_;
#pragma unroll
    for (int nt = 0; nt < 4; nt++) {
      Q[aoff + nt * 16 + l16] = f2bf(oa[nt][r] * inva);
      Q[boff + nt * 16 + l16] = f2bf(ob[nt][r] * invb);
    }
  }
}

extern "C" void kernel_launch(void* const* d_in, const int* in_sizes, int n_in,
                              void* d_out, int out_size, void* d_ws, size_t ws_size,
                              hipStream_t stream) {
  const float* x  = (const float*)d_in[0];
  const float* wq = (const float*)d_in[1];
  const float* bq = (const float*)d_in[2];
  const float* wk = (const float*)d_in[3];
  const float* bk = (const float*)d_in[4];
  const float* wv = (const float*)d_in[5];
  const float* bv = (const float*)d_in[6];
  const float* wo = (const float*)d_in[7];
  const float* bo = (const float*)d_in[8];
  const float* w1 = (const float*)d_in[9];
  const float* b1 = (const float*)d_in[10];
  const float* w2 = (const float*)d_in[11];
  const float* b2 = (const float*)d_in[12];
  const float* g1 = (const float*)d_in[13];
  const float* g2 = (const float*)d_in[14];

  // ---- workspace ----
  // [0,6):  wqT|wkT|wvT -> w2T [0,2) after O-proj
  // [6,8):  woT
  // [8,16): h -> h2
  // [16,24): Qb -> O in-place -> w1T after O-proj
  // [24,32): Kb -> f1
  // [32,40): tables (512KB, dead after gemm_qkv) -> f1
  // f1: [24,56) if ws_size >= 57MB (single-dispatch FFN), else [24,40) halves
  // d_out: VT bf16 [0,8MB) during attention -> x2 fp32 (16MB) -> final
  char* ws = (char*)d_ws;
  const size_t MB = 1024 * 1024;
  u16* qkvT = (u16*)(ws + 0 * MB);
  u16* woT  = (u16*)(ws + 6 * MB);
  u16* h    = (u16*)(ws + 8 * MB);
  u16* Qb   = (u16*)(ws + 16 * MB);
  u16* Kb   = (u16*)(ws + 24 * MB);
  float* cosT = (float*)(ws + 32 * MB);
  float* sinT = (float*)(ws + 32 * MB + 256 * 1024);
  u16* w2T  = (u16*)(ws + 0 * MB);
  u16* w1T  = (u16*)(ws + 16 * MB);
  u16* f1   = (u16*)(ws + 24 * MB);
  u16* h2   = h;
  u16* Ob   = Qb;
  u16* VT   = (u16*)d_out;
  float* x2 = (float*)d_out;
  const bool bigffn = (ws_size >= 57 * MB);

  const int MS = B_ * S_;  // 4096
  prep_qkvo<<<4096 + S_ * 32 / 256, 256, 0, stream>>>(wq, wk, wv, wo, qkvT, woT, cosT, sinT);
  rmsnorm_k<<<MS, 256, 0, stream>>>(x, g1, h);
  gemm_qkv<<<dim3(3 * D_ / 128, MS / 128), 256, 0, stream>>>(h, qkvT, bq, bk, bv, cosT, sinT, Qb, Kb, VT, MS, D_);
  flash_attn<<<dim3(S_ / 128, B_ * H_), 256, 0, stream>>>(Qb, Kb, VT);
  // x2 = O @ wo + bo + x -> d_out fp32 (VT dead); 128x64 tile -> 512 blocks
  gemm_bt<2, 4, 2><<<dim3(D_ / 64, MS / 128), 256, 0, stream>>>(Ob, woT, bo, nullptr, x2, x, MS, D_, D_);

  prep_w12<<<8192, 256, 0, stream>>>(w1, w2, w1T, w2T);  // over dead O / dead wq,wk
  rmsnorm_k<<<MS, 256, 0, stream>>>(x2, g2, h2);
  if (bigffn) {
    // single-dispatch FFN: f1 = 4096x4096 bf16 (32MB) at [24,56)
    // split-K z=4 (Kslice 1024): 1024 blocks -> 4/CU with 32KB LDS; z-local
    // XCD swizzle keeps the 4 atomic writers of each tile on one L2.
    gemm_bt<1, 4, 4><<<dim3(DFF_ / 128, MS / 128), 256, 0, stream>>>(h2, w1T, b1, f1, nullptr, nullptr, MS, DFF_, D_);
    gemm_splitk<4, 4><<<dim3(D_ / 128, MS / 128, 4), 256, 0, stream>>>(f1, w2T, b2, x2, MS, D_, 1024, DFF_);
  } else {
    for (int i = 0; i < 2; i++) {
      const u16* h2h = h2 + (size_t)i * 2048 * D_;
      float* x2h = x2 + (size_t)i * 2048 * D_;
      gemm_bt<1, 4, 4><<<dim3(DFF_ / 128, 2048 / 128), 256, 0, stream>>>(h2h, w1T, b1, f1, nullptr, nullptr, 2048, DFF_, D_);
      gemm_splitk<4, 4><<<dim3(D_ / 128, 2048 / 128, 4), 256, 0, stream>>>(f1, w2T, b2, x2h, 2048, D_, 1024, DFF_);
    }
  }
  (void)in_sizes; (void)n_in; (void)out_size;
}

// Round 10
// 340.065 us; speedup vs baseline: 1.0748x; 1.0748x over previous
//
#include <hip/hip_runtime.h>
#include <math.h>

typedef unsigned short u16;
typedef __attribute__((ext_vector_type(8))) short bf16x8;
typedef __attribute__((ext_vector_type(4))) float f32x4;
typedef __attribute__((ext_vector_type(4))) unsigned int u32x4;

#define B_ 2
#define S_ 2048
#define D_ 1024
#define H_ 16
#define DK_ 64
#define DFF_ 4096
#define EPS_ 1.1920928955078125e-07f
// (1/sqrt(64)) * log2(e)
#define EXP2SC 0.18033688011112042f

__device__ __forceinline__ float bf2f(u16 u) {
  unsigned int v = ((unsigned int)u) << 16;
  return __builtin_bit_cast(float, v);
}
__device__ __forceinline__ u16 f2bf(float f) {
  unsigned int x = __builtin_bit_cast(unsigned int, f);
  x += 0x7fffu + ((x >> 16) & 1u);   // RNE
  return (u16)(x >> 16);
}

// raw v_exp_f32 (scores bounded ~+-6: no denormal/range fixup needed; the
// default exp2f expansion is ~6 insts of OCML guard code -- pure VALU waste)
#if __has_builtin(__builtin_amdgcn_exp2f)
__device__ __forceinline__ float exp2r(float x) { return __builtin_amdgcn_exp2f(x); }
#else
__device__ __forceinline__ float exp2r(float x) { return exp2f(x); }
#endif

typedef __attribute__((address_space(3))) unsigned int lds_uint;
typedef const __attribute__((address_space(1))) unsigned int glb_uint;
__device__ __forceinline__ void gload16(const void* g, void* l) {
  __builtin_amdgcn_global_load_lds((glb_uint*)g, (lds_uint*)l, 16, 0, 0);
}

// counted vmcnt wait (T4): literal immediate via if constexpr dispatch
template <int N>
__device__ __forceinline__ void waitcnt_vm() {
  if constexpr (N == 8) asm volatile("s_waitcnt vmcnt(8)" ::: "memory");
  else if constexpr (N == 6) asm volatile("s_waitcnt vmcnt(6)" ::: "memory");
  else if constexpr (N == 4) asm volatile("s_waitcnt vmcnt(4)" ::: "memory");
  else if constexpr (N == 3) asm volatile("s_waitcnt vmcnt(3)" ::: "memory");
  else asm volatile("s_waitcnt vmcnt(0)" ::: "memory");
}

// pack two f32 -> one dword of 2 bf16 (lo = first arg)
__device__ __forceinline__ unsigned int cvtpk(float lo, float hi) {
  unsigned int d;
  asm("v_cvt_pk_bf16_f32 %0, %1, %2" : "=v"(d) : "v"(lo), "v"(hi));
  return d;
}
// swap a's upper 32 lanes with b's lower 32 lanes
__device__ __forceinline__ void plswap32(unsigned int& a, unsigned int& b) {
  asm("v_permlane32_swap_b32 %0, %1" : "+v"(a), "+v"(b));
}
// swap a's odd 16-lane rows with b's even 16-lane rows
__device__ __forceinline__ void plswap16(unsigned int& a, unsigned int& b) {
  asm("v_permlane16_swap_b32 %0, %1" : "+v"(a), "+v"(b));
}

// XCD-chunked bijective blockIdx swizzle (T1, m157): consecutive remapped ids
// share the same m-panel AND the same XCD L2. Requires gridDim.x*gridDim.y % 8 == 0.
__device__ __forceinline__ void xcd_swizzle(int& bx, int& by) {
  const int nx = gridDim.x;
  const int nwg = nx * gridDim.y;
  const int lin = blockIdx.y * nx + blockIdx.x;
  const int swz = (lin & 7) * (nwg >> 3) + (lin >> 3);
  bx = swz % nx;
  by = swz / nx;
}

// 3D variant, z FASTEST in work order: both z-slices of one (x,y) output tile
// are consecutive work items -> same XCD -> the split-K atomic RMWs of a tile
// stay in ONE L2.
__device__ __forceinline__ void xcd_swizzle3(int& bx, int& by, int& bz) {
  const int gx = gridDim.x, gy = gridDim.y, gz = gridDim.z;
  const int nb = gx * gy * gz;
  const int lin = ((int)blockIdx.z * gy + blockIdx.y) * gx + blockIdx.x;
  const int w = (lin & 7) * (nb >> 3) + (lin >> 3);
  bz = w % gz;
  const int r = w / gz;
  bx = r % gx;
  by = r / gx;
}

// ---------- fused prep 1: 4x DxD transpose+convert (wq,wk,wv,wo) + RoPE table ----------
__global__ __launch_bounds__(256) void prep_qkvo(
    const float* __restrict__ wq, const float* __restrict__ wk,
    const float* __restrict__ wv, const float* __restrict__ wo,
    u16* __restrict__ qkvT, u16* __restrict__ woT,
    float* __restrict__ cosT, float* __restrict__ sinT) {
  __shared__ float t[32][33];
  const int bid = blockIdx.x;
  const int tid = threadIdx.x;
  if (bid < 4096) {
    const int m = bid >> 10;      // 0..3: wq,wk,wv,wo
    const int tb = bid & 1023;    // 32x32 tile id
    const float* src = (m == 0) ? wq : (m == 1) ? wk : (m == 2) ? wv : wo;
    u16* dst = (m == 3) ? woT : qkvT + (size_t)m * D_ * D_;
    const int c0 = (tb & 31) * 32, r0 = (tb >> 5) * 32;
    const int tx = tid & 31, ty = tid >> 5;
#pragma unroll
    for (int i = 0; i < 32; i += 8)
      t[ty + i][tx] = src[(size_t)(r0 + ty + i) * D_ + (c0 + tx)];
    __syncthreads();
#pragma unroll
    for (int i = 0; i < 32; i += 8)
      dst[(size_t)(c0 + ty + i) * D_ + (r0 + tx)] = f2bf(t[tx][ty + i]);
  } else {
    const int idx = (bid - 4096) * 256 + tid;  // S_*32 = 65536 entries
    const int s = idx >> 5, i = idx & 31;
    double inv = exp(((double)(-2 * i) / (double)DK_) * log(10000.0));
    double ang = (double)s * inv;
    cosT[idx] = (float)cos(ang);
    sinT[idx] = (float)sin(ang);
  }
}

// ---------- fused prep 2: w1 (DxDFF) and w2 (DFFxD) transpose+convert ----------
__global__ __launch_bounds__(256) void prep_w12(
    const float* __restrict__ w1, const float* __restrict__ w2,
    u16* __restrict__ w1T, u16* __restrict__ w2T) {
  __shared__ float t[32][33];
  const int bid = blockIdx.x;
  const int tid = threadIdx.x;
  const int tx = tid & 31, ty = tid >> 5;
  if (bid < 4096) {
    // w1: R=D_, C=DFF_; tiles: 128 (C) x 32 (R)
    const int c0 = (bid & 127) * 32, r0 = (bid >> 7) * 32;
#pragma unroll
    for (int i = 0; i < 32; i += 8)
      t[ty + i][tx] = w1[(size_t)(r0 + ty + i) * DFF_ + (c0 + tx)];
    __syncthreads();
#pragma unroll
    for (int i = 0; i < 32; i += 8)
      w1T[(size_t)(c0 + ty + i) * D_ + (r0 + tx)] = f2bf(t[tx][ty + i]);
  } else {
    // w2: R=DFF_, C=D_; tiles: 32 (C) x 128 (R)
    const int b2 = bid - 4096;
    const int c0 = (b2 & 31) * 32, r0 = (b2 >> 5) * 32;
#pragma unroll
    for (int i = 0; i < 32; i += 8)
      t[ty + i][tx] = w2[(size_t)(r0 + ty + i) * D_ + (c0 + tx)];
    __syncthreads();
#pragma unroll
    for (int i = 0; i < 32; i += 8)
      w2T[(size_t)(c0 + ty + i) * DFF_ + (r0 + tx)] = f2bf(t[tx][ty + i]);
  }
}

// ---------- RMSNorm: fp32 in, bf16 out ----------
__global__ __launch_bounds__(256) void rmsnorm_k(const float* __restrict__ X,
                                                 const float* __restrict__ g,
                                                 u16* __restrict__ out) {
  const int row = blockIdx.x;
  const float* xr = X + (size_t)row * D_;
  u16* orow = out + (size_t)row * D_;
  const int tid = threadIdx.x;
  float vals[4];
  float s = 0.f;
#pragma unroll
  for (int j = 0; j < 4; j++) {
    float v = xr[tid + j * 256];
    vals[j] = v;
    s += v * v;
  }
#pragma unroll
  for (int off = 32; off > 0; off >>= 1) s += __shfl_down(s, off, 64);
  __shared__ float red[4];
  __shared__ float ssc;
  int lane = tid & 63, wave = tid >> 6;
  if (lane == 0) red[wave] = s;
  __syncthreads();
  if (tid == 0) ssc = 1.0f / sqrtf((red[0] + red[1] + red[2] + red[3]) * (1.0f / D_) + EPS_);
  __syncthreads();
  float sc = ssc;
#pragma unroll
  for (int j = 0; j < 4; j++) {
    int i = tid + j * 256;
    orow[i] = f2bf(vals[j] * sc * g[i]);
  }
}

// ===== K-loop v4 (BK=32 double-buffer, counted vmcnt): best for K=1024 GEMMs
// (qkv/FFN1/O-proj: short K-loops, grid >=3 blocks/CU; R9 A/B: ~-5us net).
#define GK_STAGE(BU, K0)                                                               \
  _Pragma("unroll")                                                                    \
  for (int c = wave; c < BM / 16; c += 4) {                                            \
    const u16* gp = gkA + (size_t)(m0 + c * 16 + lrow) * gkLD + (K0) + lcol;           \
    gload16(gp, (char*)As + __builtin_amdgcn_readfirstlane((BU) * (BM * 64) + c * 1024)); \
  }                                                                                    \
  _Pragma("unroll")                                                                    \
  for (int c = wave; c < BN / 16; c += 4) {                                            \
    const u16* gp = gkB + (size_t)(n0 + c * 16 + lrow) * gkLD + (K0) + lcol;           \
    gload16(gp, (char*)Bs + __builtin_amdgcn_readfirstlane((BU) * (BN * 64) + c * 1024)); \
  }

#define GK_COMPUTE(BU)                                                                 \
  {                                                                                    \
    bf16x8 af[WR], bfv[WC];                                                            \
    _Pragma("unroll")                                                                  \
    for (int i = 0; i < WR; i++)                                                       \
      af[i] = *(const bf16x8*)&As[(BU) * (BM * 32) + (wm + i * 16 + l16) * 32 + quad * 8]; \
    _Pragma("unroll")                                                                  \
    for (int j = 0; j < WC; j++)                                                       \
      bfv[j] = *(const bf16x8*)&Bs[(BU) * (BN * 32) + (wn + j * 16 + l16) * 32 + quad * 8]; \
    _Pragma("unroll")                                                                  \
    for (int i = 0; i < WR; i++)                                                       \
      _Pragma("unroll")                                                                \
      for (int j = 0; j < WC; j++)                                                     \
        acc[i][j] = __builtin_amdgcn_mfma_f32_16x16x32_bf16(af[i], bfv[j], acc[i][j], 0, 0, 0); \
  }

#define GEMM_KLOOP(APTR, BPTR, KLEN, KLD)                                              \
  {                                                                                    \
    const u16* gkA = (APTR);                                                           \
    const u16* gkB = (BPTR);                                                           \
    const int gkLD = (KLD);                                                            \
    GK_STAGE(0, 0)                                                                     \
    GK_STAGE(1, 32)                                                                    \
    int gkcur = 0;                                                                     \
    for (int k0 = 0; k0 < (KLEN); k0 += 32) {                                          \
      if (k0 + 32 < (KLEN)) waitcnt_vm<WR / 2 + WC / 2>();  /* older stage only */     \
      else waitcnt_vm<0>();                                 /* last tile: drain */     \
      __builtin_amdgcn_s_barrier();                                                    \
      GK_COMPUTE(gkcur)                                                                \
      __builtin_amdgcn_s_barrier();                         /* reads of buf done */    \
      if (k0 + 64 < (KLEN)) { GK_STAGE(gkcur, k0 + 64) }                               \
      gkcur ^= 1;                                                                      \
    }                                                                                  \
  }

// ===== K-loop v3 (BK=64 double-buffer, counted vmcnt): best for the K=4096
// split-K kernel -- 32 MFMAs/wave per barrier pair. (R9: BK=32 halved this
// ratio and regressed despite 2x occupancy.)
#define GK64_STAGE(BU, K0)                                                             \
  _Pragma("unroll")                                                                    \
  for (int p = 0; p < 2; p++) {                                                        \
    _Pragma("unroll")                                                                  \
    for (int c = wave; c < BM / 16; c += 4) {                                          \
      const u16* gp = gkA + (size_t)(m0 + c * 16 + lrow) * gkLD + (K0) + p * 32 + lcol; \
      gload16(gp, (char*)As + __builtin_amdgcn_readfirstlane((BU) * (BM * 128) + p * (BM * 64) + c * 1024)); \
    }                                                                                  \
    _Pragma("unroll")                                                                  \
    for (int c = wave; c < BN / 16; c += 4) {                                          \
      const u16* gp = gkB + (size_t)(n0 + c * 16 + lrow) * gkLD + (K0) + p * 32 + lcol; \
      gload16(gp, (char*)Bs + __builtin_amdgcn_readfirstlane((BU) * (BN * 128) + p * (BN * 64) + c * 1024)); \
    }                                                                                  \
  }

#define GK64_COMPUTE(BU)                                                               \
  _Pragma("unroll")                                                                    \
  for (int p = 0; p < 2; p++) {                                                        \
    bf16x8 af[WR], bfv[WC];                                                            \
    _Pragma("unroll")                                                                  \
    for (int i = 0; i < WR; i++)                                                       \
      af[i] = *(const bf16x8*)&As[(BU) * (BM * 64) + p * (BM * 32) + (wm + i * 16 + l16) * 32 + quad * 8]; \
    _Pragma("unroll")                                                                  \
    for (int j = 0; j < WC; j++)                                                       \
      bfv[j] = *(const bf16x8*)&Bs[(BU) * (BN * 64) + p * (BN * 32) + (wn + j * 16 + l16) * 32 + quad * 8]; \
    _Pragma("unroll")                                                                  \
    for (int i = 0; i < WR; i++)                                                       \
      _Pragma("unroll")                                                                \
      for (int j = 0; j < WC; j++)                                                     \
        acc[i][j] = __builtin_amdgcn_mfma_f32_16x16x32_bf16(af[i], bfv[j], acc[i][j], 0, 0, 0); \
  }

#define GEMM_KLOOP64(APTR, BPTR, KLEN, KLD)                                            \
  {                                                                                    \
    const u16* gkA = (APTR);                                                           \
    const u16* gkB = (BPTR);                                                           \
    const int gkLD = (KLD);                                                            \
    GK64_STAGE(0, 0)                                                                   \
    GK64_STAGE(1, 64)                                                                  \
    int gkcur = 0;                                                                     \
    for (int k0 = 0; k0 < (KLEN); k0 += 64) {                                          \
      if (k0 + 64 < (KLEN)) waitcnt_vm<WR + WC>();  /* older stage done; newer in flight */ \
      else waitcnt_vm<0>();                         /* last tile: drain */             \
      __builtin_amdgcn_s_barrier();                                                    \
      GK64_COMPUTE(gkcur)                                                              \
      __builtin_amdgcn_s_barrier();                 /* all reads of buf done */        \
      if (k0 + 128 < (KLEN)) { GK64_STAGE(gkcur, k0 + 128) }                           \
      gkcur ^= 1;                                                                      \
    }                                                                                  \
  }

// ---------- generic GEMM: MODE 0 bf16, MODE 1 relu->bf16, MODE 2 fp32 = v + resF ----------
template <int MODE, int WR, int WC>
__global__ __launch_bounds__(256, 4) void gemm_bt(
    const u16* __restrict__ A, const u16* __restrict__ Bt, const float* __restrict__ bias,
    u16* __restrict__ outB, float* __restrict__ outF, const float* __restrict__ resF,
    int M, int N, int K) {
  constexpr int BM = 2 * WR * 16;
  constexpr int BN = 2 * WC * 16;
  __shared__ u16 As[2 * BM * 32];
  __shared__ u16 Bs[2 * BN * 32];
  const int tid = threadIdx.x;
  const int wave = tid >> 6, lane = tid & 63, quad = lane >> 4, l16 = lane & 15;
  const int wm = (wave >> 1) * (WR * 16), wn = (wave & 1) * (WC * 16);
  int bx, by;
  xcd_swizzle(bx, by);
  const int m0 = by * BM, n0 = bx * BN;
  const int lrow = lane >> 2, lcol = (lane & 3) * 8;
  f32x4 acc[WR][WC] = {};
  GEMM_KLOOP(A, Bt, K, K)
#pragma unroll
  for (int i = 0; i < WR; i++)
#pragma unroll
    for (int j = 0; j < WC; j++) {
      int col = n0 + wn + j * 16 + l16;
      float bv = bias[col];
#pragma unroll
      for (int r = 0; r < 4; r++) {
        int row = m0 + wm + i * 16 + quad * 4 + r;
        size_t off = (size_t)row * N + col;
        float v = acc[i][j][r] + bv;
        if constexpr (MODE == 1) v = fmaxf(v, 0.f);
        if constexpr (MODE == 2) outF[off] = v + resF[off];
        else outB[off] = f2bf(v);
      }
    }
}

// ---------- fused QKV GEMM + RoPE (table-based): Bt = [wqT;wkT;wvT] ----------
// Q is additionally pre-scaled by EXP2SC (softmax exp2 scale folded in; Q buf
// is consumed only by flash_attn).
__global__ __launch_bounds__(256, 4) void gemm_qkv(
    const u16* __restrict__ A, const u16* __restrict__ Bt,
    const float* __restrict__ bq, const float* __restrict__ bk, const float* __restrict__ bv,
    const float* __restrict__ cosT, const float* __restrict__ sinT,
    u16* __restrict__ Qb, u16* __restrict__ Kb, u16* __restrict__ VT, int M, int K) {
  constexpr int WR = 4, WC = 4;
  constexpr int BM = 128, BN = 128;
  __shared__ u16 As[2 * BM * 32];
  __shared__ u16 Bs[2 * BN * 32];
  const int tid = threadIdx.x;
  const int wave = tid >> 6, lane = tid & 63, quad = lane >> 4, l16 = lane & 15;
  const int wm = (wave >> 1) * 64, wn = (wave & 1) * 64;
  int bx, by;
  xcd_swizzle(bx, by);
  const int m0 = by * BM, n0 = bx * BN;
  const int lrow = lane >> 2, lcol = (lane & 3) * 8;
  f32x4 acc[WR][WC] = {};
  GEMM_KLOOP(A, Bt, K, K)
  const int g = n0 >> 10;  // whole tile is one of Q/K/V (BN=128 divides 1024)
  if (g < 2) {
    // Q or K with fused RoPE via table. Pair (jp, jp+2): cols c0 and c0+32 (same head).
    u16* dst = (g == 0) ? Qb : Kb;
    const float* bias = (g == 0) ? bq : bk;
    const float scq = (g == 0) ? EXP2SC : 1.0f;
#pragma unroll
    for (int i = 0; i < WR; i++)
#pragma unroll
      for (int jp = 0; jp < 2; jp++) {
        int col0 = n0 + wn + jp * 16 + l16;
        int c0 = col0 & 1023;               // dk = c0&63 in [0,32)
        float bv0 = bias[c0], bv1 = bias[c0 + 32];
        int irot = jp * 16 + l16;           // rotation index (0..31)
        int row0 = m0 + wm + i * 16 + quad * 4;
#pragma unroll
        for (int r = 0; r < 4; r++) {
          int row = row0 + r;
          int s2 = row & 2047;
          float cs = cosT[s2 * 32 + irot];
          float sn = sinT[s2 * 32 + irot];
          float x0 = acc[i][jp][r] + bv0;
          float x1 = acc[i][jp + 2][r] + bv1;
          dst[(size_t)row * D_ + c0]      = f2bf((x0 * cs - x1 * sn) * scq);
          dst[(size_t)row * D_ + c0 + 32] = f2bf((x1 * cs + x0 * sn) * scq);
        }
      }
  } else {
#pragma unroll
    for (int i = 0; i < WR; i++)
#pragma unroll
      for (int j = 0; j < WC; j++) {
        int col = n0 + wn + j * 16 + l16;
        int c = col & 1023;
        float bvv = bv[c];
        int row0 = m0 + wm + i * 16 + quad * 4;
        int hh = c >> 6, dk = c & 63;
        int b = row0 >> 11, s2 = row0 & 2047;
        ushort4 pv;
        pv.x = f2bf(acc[i][j][0] + bvv);
        pv.y = f2bf(acc[i][j][1] + bvv);
        pv.z = f2bf(acc[i][j][2] + bvv);
        pv.w = f2bf(acc[i][j][3] + bvv);
        *(ushort4*)&VT[(((size_t)(b * H_ + hh)) * DK_ + dk) * S_ + s2] = pv;
      }
  }
}

// ---------- split-K GEMM, fp32 atomic-add epilogue (residual pre-loaded in outF) ----------
// R8-best config: BK=64 v3 loop (32 MFMAs/wave per barrier pair), z=2.
// z-fastest XCD swizzle keeps both atomic writers of a tile on one L2.
template <int WR, int WC>
__global__ __launch_bounds__(256) void gemm_splitk(
    const u16* __restrict__ A, const u16* __restrict__ Bt, const float* __restrict__ bias,
    float* outF, int M, int N, int Kslice, int Kld) {
  constexpr int BM = 2 * WR * 16;
  constexpr int BN = 2 * WC * 16;
  __shared__ u16 As[2 * BM * 64];
  __shared__ u16 Bs[2 * BN * 64];
  const int tid = threadIdx.x;
  const int wave = tid >> 6, lane = tid & 63, quad = lane >> 4, l16 = lane & 15;
  const int wm = (wave >> 1) * (WR * 16), wn = (wave & 1) * (WC * 16);
  int bx, by, bz;
  xcd_swizzle3(bx, by, bz);
  const int m0 = by * BM, n0 = bx * BN;
  const int lrow = lane >> 2, lcol = (lane & 3) * 8;
  const u16* Ao = A + (size_t)bz * Kslice;
  const u16* Bo = Bt + (size_t)bz * Kslice;
  f32x4 acc[WR][WC] = {};
  GEMM_KLOOP64(Ao, Bo, Kslice, Kld)
  const bool addb = (bz == 0);
#pragma unroll
  for (int i = 0; i < WR; i++)
#pragma unroll
    for (int j = 0; j < WC; j++) {
      int col = n0 + wn + j * 16 + l16;
      float bv = addb ? bias[col] : 0.f;
#pragma unroll
      for (int r = 0; r < 4; r++) {
        int row = m0 + wm + i * 16 + quad * 4 + r;
        unsafeAtomicAdd(&outF[(size_t)row * N + col], acc[i][j][r] + bv);
      }
    }
}

// ---------- flash attention v5 ----------
// 128 q-rows/block (4 waves x 32 q), 64-key tiles double-buffered with the
// T4 counted-vmcnt schedule. 32KB LDS -> 4 blocks/CU = 4 waves/SIMD.
// Swapped QK^T; P in-register (cvt_pk + permlane); raw v_exp_f32 (exp2r);
// softmax denominator via MFMA ones-trick.
__device__ __forceinline__ void softmax_pack(f32x4 s0, f32x4 s1, f32x4 s2, f32x4 s3,
                                             bf16x8& pf0, bf16x8& pf1) {
  f32x4 p0, p1, p2, p3;
#pragma unroll
  for (int r = 0; r < 4; r++) {
    p0[r] = exp2r(s0[r]);
    p1[r] = exp2r(s1[r]);
    p2[r] = exp2r(s2[r]);
    p3[r] = exp2r(s3[r]);
  }
  unsigned int X0 = cvtpk(p0[0], p0[1]), X1 = cvtpk(p0[2], p0[3]);
  unsigned int Y0 = cvtpk(p1[0], p1[1]), Y1 = cvtpk(p1[2], p1[3]);
  unsigned int Z0 = cvtpk(p2[0], p2[1]), Z1 = cvtpk(p2[2], p2[3]);
  unsigned int W0 = cvtpk(p3[0], p3[1]), W1 = cvtpk(p3[2], p3[3]);
  // redistribute: after (swap32; swap16), first reg = dword j, second = dword j+2
  plswap32(X0, Y0); plswap16(X0, Y0);
  plswap32(X1, Y1); plswap16(X1, Y1);
  plswap32(Z0, W0); plswap16(Z0, W0);
  plswap32(Z1, W1); plswap16(Z1, W1);
  u32x4 lo = {X0, X1, Y0, Y1};
  u32x4 hi = {Z0, Z1, W0, W1};
  pf0 = __builtin_bit_cast(bf16x8, lo);
  pf1 = __builtin_bit_cast(bf16x8, hi);
}

__global__ __launch_bounds__(256, 4) void flash_attn(u16* __restrict__ Q,
                                                     const u16* __restrict__ Kg,
                                                     const u16* __restrict__ VT) {
  const int bh = blockIdx.y;
  const int b = bh >> 4, h = bh & 15;
  const int q0 = blockIdx.x * 128;
  const int tid = threadIdx.x;
  const int wave = tid >> 6, lane = tid & 63, quad = lane >> 4, l16 = lane & 15;
  const size_t base = (size_t)b * S_ * D_ + h * DK_;
  const size_t vbase = (size_t)bh * DK_ * S_;

  __shared__ u16 Ks[2][4096];   // per buf [64key][64dk]: byte = key*128 + (colb ^ ((key&7)<<4))
  __shared__ u16 Vts[2][4096];  // per buf [64dk][64key]: byte = dk*128  + (colb ^ ((dk&7)<<4))

  // staging: wave w covers rows w*16..w*16+15 (8 lanes/row, 2 gloads of 8 rows)
  const int srow8 = lane >> 3;                        // 0..7
  const int scol = ((lane & 7) ^ srow8) * 8;          // pre-swizzled u16 col
  const int kkey = wave * 16 + srow8;                 // +c*8 ; kkey&7 == srow8
  const u16* kp0 = Kg + base + (size_t)kkey * D_ + scol;
  const int vdk = wave * 16 + srow8;                  // +c*8 ; vdk&7 == srow8
  const u16* vp0 = VT + vbase + (size_t)vdk * S_ + scol;

#define FA_STAGE(BU, KT)                                                               \
  _Pragma("unroll")                                                                    \
  for (int c = 0; c < 2; c++) {                                                        \
    gload16(kp0 + (size_t)((KT) + c * 8) * D_,                                         \
            (char*)Ks + __builtin_amdgcn_readfirstlane((BU) * 8192 + wave * 2048 + c * 1024)); \
    gload16(vp0 + (size_t)(c * 8) * S_ + (KT),                                         \
            (char*)Vts + __builtin_amdgcn_readfirstlane((BU) * 8192 + wave * 2048 + c * 1024)); \
  }

  FA_STAGE(0, 0)
  FA_STAGE(1, 64)

  // Q fragments: qset a = rows wave*32+l16, qset b = +16; cols quad*8 (+32)
  const size_t qoffA = base + (size_t)(q0 + wave * 32 + l16) * D_ + quad * 8;
  const size_t qoffB = qoffA + (size_t)16 * D_;
  bf16x8 qa0 = *(const bf16x8*)(Q + qoffA);
  bf16x8 qa1 = *(const bf16x8*)(Q + qoffA + 32);
  bf16x8 qb0 = *(const bf16x8*)(Q + qoffB);
  bf16x8 qb1 = *(const bf16x8*)(Q + qoffB + 32);

  f32x4 oa[4] = {}, ob[4] = {};
  f32x4 lsa_acc = {}, lsb_acc = {};
  const u32x4 onesu = {0x3F803F80u, 0x3F803F80u, 0x3F803F80u, 0x3F803F80u};
  const bf16x8 ones = __builtin_bit_cast(bf16x8, onesu);
  const int sw = (l16 & 7) << 4;

#define FA_TILE(BU)                                                                    \
  {                                                                                    \
    const char* KsB = (const char*)Ks + (BU) * 8192;                                   \
    const char* VtsB = (const char*)Vts + (BU) * 8192;                                 \
    f32x4 sa[4] = {}, sb[4] = {};                                                      \
    __builtin_amdgcn_s_setprio(1);                                                     \
    _Pragma("unroll")                                                                  \
    for (int nt = 0; nt < 4; nt++) {                                                   \
      const char* krow = KsB + (nt * 16 + l16) * 128;                                  \
      bf16x8 k0 = *(const bf16x8*)(krow + ((quad * 16) ^ sw));                         \
      bf16x8 k1 = *(const bf16x8*)(krow + ((64 + quad * 16) ^ sw));                    \
      sa[nt] = __builtin_amdgcn_mfma_f32_16x16x32_bf16(k0, qa0, sa[nt], 0, 0, 0);      \
      sa[nt] = __builtin_amdgcn_mfma_f32_16x16x32_bf16(k1, qa1, sa[nt], 0, 0, 0);      \
      sb[nt] = __builtin_amdgcn_mfma_f32_16x16x32_bf16(k0, qb0, sb[nt], 0, 0, 0);      \
      sb[nt] = __builtin_amdgcn_mfma_f32_16x16x32_bf16(k1, qb1, sb[nt], 0, 0, 0);      \
    }                                                                                  \
    __builtin_amdgcn_s_setprio(0);                                                     \
    bf16x8 pa0, pa1, pb0, pb1;                                                         \
    softmax_pack(sa[0], sa[1], sa[2], sa[3], pa0, pa1);                                \
    softmax_pack(sb[0], sb[1], sb[2], sb[3], pb0, pb1);                                \
    __builtin_amdgcn_s_setprio(1);                                                     \
    lsa_acc = __builtin_amdgcn_mfma_f32_16x16x32_bf16(pa0, ones, lsa_acc, 0, 0, 0);    \
    lsa_acc = __builtin_amdgcn_mfma_f32_16x16x32_bf16(pa1, ones, lsa_acc, 0, 0, 0);    \
    lsb_acc = __builtin_amdgcn_mfma_f32_16x16x32_bf16(pb0, ones, lsb_acc, 0, 0, 0);    \
    lsb_acc = __builtin_amdgcn_mfma_f32_16x16x32_bf16(pb1, ones, lsb_acc, 0, 0, 0);    \
    _Pragma("unroll")                                                                  \
    for (int nt = 0; nt < 4; nt++) {                                                   \
      const char* vrow = VtsB + (nt * 16 + l16) * 128;                                 \
      bf16x8 v0 = *(const bf16x8*)(vrow + ((quad * 16) ^ sw));                         \
      bf16x8 v1 = *(const bf16x8*)(vrow + ((64 + quad * 16) ^ sw));                    \
      oa[nt] = __builtin_amdgcn_mfma_f32_16x16x32_bf16(pa0, v0, oa[nt], 0, 0, 0);      \
      oa[nt] = __builtin_amdgcn_mfma_f32_16x16x32_bf16(pa1, v1, oa[nt], 0, 0, 0);      \
      ob[nt] = __builtin_amdgcn_mfma_f32_16x16x32_bf16(pb0, v0, ob[nt], 0, 0, 0);      \
      ob[nt] = __builtin_amdgcn_mfma_f32_16x16x32_bf16(pb1, v1, ob[nt], 0, 0, 0);      \
    }                                                                                  \
    __builtin_amdgcn_s_setprio(0);                                                     \
  }

  // T4 schedule: vmcnt(4) retires only the older stage; the newer one stays
  // in flight across both barriers, hidden under a full tile of MFMA+VALU.
  int cur = 0;
  for (int kt = 0; kt < S_; kt += 64) {
    if (kt + 64 < S_) waitcnt_vm<4>();
    else waitcnt_vm<0>();
    __builtin_amdgcn_s_barrier();
    FA_TILE(cur)
    __builtin_amdgcn_s_barrier();
    if (kt + 128 < S_) { FA_STAGE(cur, kt + 128) }
    cur ^= 1;
  }
#undef FA_STAGE
#undef FA_TILE

  // lsX_acc[r] holds sum_k P[q][k] for q = quad*4+r on every l16 lane --
  // exactly the rows oa/ob[nt][r] cover; no cross-lane reduction needed.
#pragma unroll
  for (int r = 0; r < 4; r++) {
    float inva = 1.0f / lsa_acc[r];
    float invb = 1.0f / lsb_acc[r];
    const size_t aoff = base + (size_t)(q0 + wave * 32 + quad * 4 + r) * D_;
    const size_t boff = aoff + (size_t)16 * D_;
#pragma unroll
    for (int nt = 0; nt < 4; nt++) {
      Q[aoff + nt * 16 + l16] = f2bf(oa[nt][r] * inva);
      Q[boff + nt * 16 + l16] = f2bf(ob[nt][r] * invb);
    }
  }
}

extern "C" void kernel_launch(void* const* d_in, const int* in_sizes, int n_in,
                              void* d_out, int out_size, void* d_ws, size_t ws_size,
                              hipStream_t stream) {
  const float* x  = (const float*)d_in[0];
  const float* wq = (const float*)d_in[1];
  const float* bq = (const float*)d_in[2];
  const float* wk = (const float*)d_in[3];
  const float* bk = (const float*)d_in[4];
  const float* wv = (const float*)d_in[5];
  const float* bv = (const float*)d_in[6];
  const float* wo = (const float*)d_in[7];
  const float* bo = (const float*)d_in[8];
  const float* w1 = (const float*)d_in[9];
  const float* b1 = (const float*)d_in[10];
  const float* w2 = (const float*)d_in[11];
  const float* b2 = (const float*)d_in[12];
  const float* g1 = (const float*)d_in[13];
  const float* g2 = (const float*)d_in[14];

  // ---- workspace ----
  // [0,6):  wqT|wkT|wvT -> w2T [0,2) after O-proj
  // [6,8):  woT
  // [8,16): h -> h2
  // [16,24): Qb -> O in-place -> w1T after O-proj
  // [24,32): Kb -> f1
  // [32,40): tables (512KB, dead after gemm_qkv) -> f1
  // f1: [24,56) if ws_size >= 57MB (single-dispatch FFN), else [24,40) halves
  // d_out: VT bf16 [0,8MB) during attention -> x2 fp32 (16MB) -> final
  char* ws = (char*)d_ws;
  const size_t MB = 1024 * 1024;
  u16* qkvT = (u16*)(ws + 0 * MB);
  u16* woT  = (u16*)(ws + 6 * MB);
  u16* h    = (u16*)(ws + 8 * MB);
  u16* Qb   = (u16*)(ws + 16 * MB);
  u16* Kb   = (u16*)(ws + 24 * MB);
  float* cosT = (float*)(ws + 32 * MB);
  float* sinT = (float*)(ws + 32 * MB + 256 * 1024);
  u16* w2T  = (u16*)(ws + 0 * MB);
  u16* w1T  = (u16*)(ws + 16 * MB);
  u16* f1   = (u16*)(ws + 24 * MB);
  u16* h2   = h;
  u16* Ob   = Qb;
  u16* VT   = (u16*)d_out;
  float* x2 = (float*)d_out;
  const bool bigffn = (ws_size >= 57 * MB);

  const int MS = B_ * S_;  // 4096
  prep_qkvo<<<4096 + S_ * 32 / 256, 256, 0, stream>>>(wq, wk, wv, wo, qkvT, woT, cosT, sinT);
  rmsnorm_k<<<MS, 256, 0, stream>>>(x, g1, h);
  gemm_qkv<<<dim3(3 * D_ / 128, MS / 128), 256, 0, stream>>>(h, qkvT, bq, bk, bv, cosT, sinT, Qb, Kb, VT, MS, D_);
  flash_attn<<<dim3(S_ / 128, B_ * H_), 256, 0, stream>>>(Qb, Kb, VT);
  // x2 = O @ wo + bo + x -> d_out fp32 (VT dead); 128x64 tile -> 512 blocks
  gemm_bt<2, 4, 2><<<dim3(D_ / 64, MS / 128), 256, 0, stream>>>(Ob, woT, bo, nullptr, x2, x, MS, D_, D_);

  prep_w12<<<8192, 256, 0, stream>>>(w1, w2, w1T, w2T);  // over dead O / dead wq,wk
  rmsnorm_k<<<MS, 256, 0, stream>>>(x2, g2, h2);
  if (bigffn) {
    // single-dispatch FFN: f1 = 4096x4096 bf16 (32MB) at [24,56)
    // split-K z=2 (Kslice 2048): R8-best; z-local swizzle for atomic locality.
    gemm_bt<1, 4, 4><<<dim3(DFF_ / 128, MS / 128), 256, 0, stream>>>(h2, w1T, b1, f1, nullptr, nullptr, MS, DFF_, D_);
    gemm_splitk<4, 4><<<dim3(D_ / 128, MS / 128, 2), 256, 0, stream>>>(f1, w2T, b2, x2, MS, D_, 2048, DFF_);
  } else {
    for (int i = 0; i < 2; i++) {
      const u16* h2h = h2 + (size_t)i * 2048 * D_;
      float* x2h = x2 + (size_t)i * 2048 * D_;
      gemm_bt<1, 4, 4><<<dim3(DFF_ / 128, 2048 / 128), 256, 0, stream>>>(h2h, w1T, b1, f1, nullptr, nullptr, 2048, DFF_, D_);
      gemm_splitk<4, 4><<<dim3(D_ / 128, 2048 / 128, 4), 256, 0, stream>>>(f1, w2T, b2, x2h, 2048, D_, 1024, DFF_);
    }
  }
  (void)in_sizes; (void)n_in; (void)out_size;
}

// Round 11
// 339.029 us; speedup vs baseline: 1.0780x; 1.0031x over previous
//
#include <hip/hip_runtime.h>
#include <math.h>

typedef unsigned short u16;
typedef __attribute__((ext_vector_type(8))) short bf16x8;
typedef __attribute__((ext_vector_type(4))) float f32x4;
typedef __attribute__((ext_vector_type(4))) unsigned int u32x4;

#define B_ 2
#define S_ 2048
#define D_ 1024
#define H_ 16
#define DK_ 64
#define DFF_ 4096
#define EPS_ 1.1920928955078125e-07f
// (1/sqrt(64)) * log2(e)
#define EXP2SC 0.18033688011112042f

__device__ __forceinline__ float bf2f(u16 u) {
  unsigned int v = ((unsigned int)u) << 16;
  return __builtin_bit_cast(float, v);
}
__device__ __forceinline__ u16 f2bf(float f) {
  unsigned int x = __builtin_bit_cast(unsigned int, f);
  x += 0x7fffu + ((x >> 16) & 1u);   // RNE
  return (u16)(x >> 16);
}

// raw v_exp_f32 (scores bounded ~+-6: no denormal/range fixup needed; the
// default exp2f expansion is ~6 insts of OCML guard code -- pure VALU waste)
#if __has_builtin(__builtin_amdgcn_exp2f)
__device__ __forceinline__ float exp2r(float x) { return __builtin_amdgcn_exp2f(x); }
#else
__device__ __forceinline__ float exp2r(float x) { return exp2f(x); }
#endif

typedef __attribute__((address_space(3))) unsigned int lds_uint;
typedef const __attribute__((address_space(1))) unsigned int glb_uint;
__device__ __forceinline__ void gload16(const void* g, void* l) {
  __builtin_amdgcn_global_load_lds((glb_uint*)g, (lds_uint*)l, 16, 0, 0);
}

// counted vmcnt wait (T4): literal immediate via if constexpr dispatch
template <int N>
__device__ __forceinline__ void waitcnt_vm() {
  if constexpr (N == 8) asm volatile("s_waitcnt vmcnt(8)" ::: "memory");
  else if constexpr (N == 6) asm volatile("s_waitcnt vmcnt(6)" ::: "memory");
  else if constexpr (N == 4) asm volatile("s_waitcnt vmcnt(4)" ::: "memory");
  else if constexpr (N == 3) asm volatile("s_waitcnt vmcnt(3)" ::: "memory");
  else asm volatile("s_waitcnt vmcnt(0)" ::: "memory");
}

// pack two f32 -> one dword of 2 bf16 (lo = first arg)
__device__ __forceinline__ unsigned int cvtpk(float lo, float hi) {
  unsigned int d;
  asm("v_cvt_pk_bf16_f32 %0, %1, %2" : "=v"(d) : "v"(lo), "v"(hi));
  return d;
}
// swap a's upper 32 lanes with b's lower 32 lanes
__device__ __forceinline__ void plswap32(unsigned int& a, unsigned int& b) {
  asm("v_permlane32_swap_b32 %0, %1" : "+v"(a), "+v"(b));
}
// swap a's odd 16-lane rows with b's even 16-lane rows
__device__ __forceinline__ void plswap16(unsigned int& a, unsigned int& b) {
  asm("v_permlane16_swap_b32 %0, %1" : "+v"(a), "+v"(b));
}

// XCD-chunked bijective blockIdx swizzle (T1, m157): consecutive remapped ids
// share the same m-panel AND the same XCD L2. Requires gridDim.x*gridDim.y % 8 == 0.
__device__ __forceinline__ void xcd_swizzle(int& bx, int& by) {
  const int nx = gridDim.x;
  const int nwg = nx * gridDim.y;
  const int lin = blockIdx.y * nx + blockIdx.x;
  const int swz = (lin & 7) * (nwg >> 3) + (lin >> 3);
  bx = swz % nx;
  by = swz / nx;
}

// 3D variant, z FASTEST in work order: both z-slices of one (x,y) output tile
// are consecutive work items -> same XCD -> the split-K atomic RMWs of a tile
// stay in ONE L2.
__device__ __forceinline__ void xcd_swizzle3(int& bx, int& by, int& bz) {
  const int gx = gridDim.x, gy = gridDim.y, gz = gridDim.z;
  const int nb = gx * gy * gz;
  const int lin = ((int)blockIdx.z * gy + blockIdx.y) * gx + blockIdx.x;
  const int w = (lin & 7) * (nb >> 3) + (lin >> 3);
  bz = w % gz;
  const int r = w / gz;
  bx = r % gx;
  by = r / gx;
}

// ---------- fused prep 1: 4x DxD transpose+convert (wq,wk,wv,wo) + RoPE table ----------
__global__ __launch_bounds__(256) void prep_qkvo(
    const float* __restrict__ wq, const float* __restrict__ wk,
    const float* __restrict__ wv, const float* __restrict__ wo,
    u16* __restrict__ qkvT, u16* __restrict__ woT,
    float* __restrict__ cosT, float* __restrict__ sinT) {
  __shared__ float t[32][33];
  const int bid = blockIdx.x;
  const int tid = threadIdx.x;
  if (bid < 4096) {
    const int m = bid >> 10;      // 0..3: wq,wk,wv,wo
    const int tb = bid & 1023;    // 32x32 tile id
    const float* src = (m == 0) ? wq : (m == 1) ? wk : (m == 2) ? wv : wo;
    u16* dst = (m == 3) ? woT : qkvT + (size_t)m * D_ * D_;
    const int c0 = (tb & 31) * 32, r0 = (tb >> 5) * 32;
    const int tx = tid & 31, ty = tid >> 5;
#pragma unroll
    for (int i = 0; i < 32; i += 8)
      t[ty + i][tx] = src[(size_t)(r0 + ty + i) * D_ + (c0 + tx)];
    __syncthreads();
#pragma unroll
    for (int i = 0; i < 32; i += 8)
      dst[(size_t)(c0 + ty + i) * D_ + (r0 + tx)] = f2bf(t[tx][ty + i]);
  } else {
    const int idx = (bid - 4096) * 256 + tid;  // S_*32 = 65536 entries
    const int s = idx >> 5, i = idx & 31;
    double inv = exp(((double)(-2 * i) / (double)DK_) * log(10000.0));
    double ang = (double)s * inv;
    cosT[idx] = (float)cos(ang);
    sinT[idx] = (float)sin(ang);
  }
}

// ---------- fused prep 2: w1 (DxDFF) and w2 (DFFxD) transpose+convert ----------
__global__ __launch_bounds__(256) void prep_w12(
    const float* __restrict__ w1, const float* __restrict__ w2,
    u16* __restrict__ w1T, u16* __restrict__ w2T) {
  __shared__ float t[32][33];
  const int bid = blockIdx.x;
  const int tid = threadIdx.x;
  const int tx = tid & 31, ty = tid >> 5;
  if (bid < 4096) {
    // w1: R=D_, C=DFF_; tiles: 128 (C) x 32 (R)
    const int c0 = (bid & 127) * 32, r0 = (bid >> 7) * 32;
#pragma unroll
    for (int i = 0; i < 32; i += 8)
      t[ty + i][tx] = w1[(size_t)(r0 + ty + i) * DFF_ + (c0 + tx)];
    __syncthreads();
#pragma unroll
    for (int i = 0; i < 32; i += 8)
      w1T[(size_t)(c0 + ty + i) * D_ + (r0 + tx)] = f2bf(t[tx][ty + i]);
  } else {
    // w2: R=DFF_, C=D_; tiles: 32 (C) x 128 (R)
    const int b2 = bid - 4096;
    const int c0 = (b2 & 31) * 32, r0 = (b2 >> 5) * 32;
#pragma unroll
    for (int i = 0; i < 32; i += 8)
      t[ty + i][tx] = w2[(size_t)(r0 + ty + i) * D_ + (c0 + tx)];
    __syncthreads();
#pragma unroll
    for (int i = 0; i < 32; i += 8)
      w2T[(size_t)(c0 + ty + i) * DFF_ + (r0 + tx)] = f2bf(t[tx][ty + i]);
  }
}

// ---------- RMSNorm: fp32 in, bf16 out ----------
__global__ __launch_bounds__(256) void rmsnorm_k(const float* __restrict__ X,
                                                 const float* __restrict__ g,
                                                 u16* __restrict__ out) {
  const int row = blockIdx.x;
  const float* xr = X + (size_t)row * D_;
  u16* orow = out + (size_t)row * D_;
  const int tid = threadIdx.x;
  float vals[4];
  float s = 0.f;
#pragma unroll
  for (int j = 0; j < 4; j++) {
    float v = xr[tid + j * 256];
    vals[j] = v;
    s += v * v;
  }
#pragma unroll
  for (int off = 32; off > 0; off >>= 1) s += __shfl_down(s, off, 64);
  __shared__ float red[4];
  __shared__ float ssc;
  int lane = tid & 63, wave = tid >> 6;
  if (lane == 0) red[wave] = s;
  __syncthreads();
  if (tid == 0) ssc = 1.0f / sqrtf((red[0] + red[1] + red[2] + red[3]) * (1.0f / D_) + EPS_);
  __syncthreads();
  float sc = ssc;
#pragma unroll
  for (int j = 0; j < 4; j++) {
    int i = tid + j * 256;
    orow[i] = f2bf(vals[j] * sc * g[i]);
  }
}

// ===== LDS slot-swizzle (T2, rule #21 both-sides) =====
// Image invariant per 32-u16 panel row: LDS[row][slot] = G[row][slot ^ (row&3)]
// (16B slots, involution). Staging keeps the LDS dest LINEAR (global_load_lds
// can't scatter) and pre-swizzles the per-lane GLOBAL column:
//   lcol = ((lane&3) ^ (lrow&3)) * 8   [lane&3 = slot it writes, lrow = row]
// Reads access slot quad ^ (row&3); row&3 == l16&3 for every fragment row
// (all row offsets are multiples of 16), so qsw = (quad ^ (l16&3)) * 8.
// Effect: intra-beat bank aliasing of the 64B-stride ds_read_b128 pattern
// drops 4-way -> 2-way (free, m136). R10 PMC: +4 extra cyc/read, 4.19M
// conflicts/dispatch -- the largest single component of the GEMM K-iter.

// ===== K-loop v4 (BK=32 double-buffer, counted vmcnt): K=1024 GEMMs =====
#define GK_STAGE(BU, K0)                                                               \
  _Pragma("unroll")                                                                    \
  for (int c = wave; c < BM / 16; c += 4) {                                            \
    const u16* gp = gkA + (size_t)(m0 + c * 16 + lrow) * gkLD + (K0) + lcol;           \
    gload16(gp, (char*)As + __builtin_amdgcn_readfirstlane((BU) * (BM * 64) + c * 1024)); \
  }                                                                                    \
  _Pragma("unroll")                                                                    \
  for (int c = wave; c < BN / 16; c += 4) {                                            \
    const u16* gp = gkB + (size_t)(n0 + c * 16 + lrow) * gkLD + (K0) + lcol;           \
    gload16(gp, (char*)Bs + __builtin_amdgcn_readfirstlane((BU) * (BN * 64) + c * 1024)); \
  }

#define GK_COMPUTE(BU)                                                                 \
  {                                                                                    \
    bf16x8 af[WR], bfv[WC];                                                            \
    _Pragma("unroll")                                                                  \
    for (int i = 0; i < WR; i++)                                                       \
      af[i] = *(const bf16x8*)&As[(BU) * (BM * 32) + (wm + i * 16 + l16) * 32 + qsw];  \
    _Pragma("unroll")                                                                  \
    for (int j = 0; j < WC; j++)                                                       \
      bfv[j] = *(const bf16x8*)&Bs[(BU) * (BN * 32) + (wn + j * 16 + l16) * 32 + qsw]; \
    _Pragma("unroll")                                                                  \
    for (int i = 0; i < WR; i++)                                                       \
      _Pragma("unroll")                                                                \
      for (int j = 0; j < WC; j++)                                                     \
        acc[i][j] = __builtin_amdgcn_mfma_f32_16x16x32_bf16(af[i], bfv[j], acc[i][j], 0, 0, 0); \
  }

#define GEMM_KLOOP(APTR, BPTR, KLEN, KLD)                                              \
  {                                                                                    \
    const u16* gkA = (APTR);                                                           \
    const u16* gkB = (BPTR);                                                           \
    const int gkLD = (KLD);                                                            \
    GK_STAGE(0, 0)                                                                     \
    GK_STAGE(1, 32)                                                                    \
    int gkcur = 0;                                                                     \
    for (int k0 = 0; k0 < (KLEN); k0 += 32) {                                          \
      if (k0 + 32 < (KLEN)) waitcnt_vm<WR / 2 + WC / 2>();  /* older stage only */     \
      else waitcnt_vm<0>();                                 /* last tile: drain */     \
      __builtin_amdgcn_s_barrier();                                                    \
      GK_COMPUTE(gkcur)                                                                \
      __builtin_amdgcn_s_barrier();                         /* reads of buf done */    \
      if (k0 + 64 < (KLEN)) { GK_STAGE(gkcur, k0 + 64) }                               \
      gkcur ^= 1;                                                                      \
    }                                                                                  \
  }

// ===== K-loop v3 (BK=64 double-buffer, counted vmcnt): K=4096 split-K =====
#define GK64_STAGE(BU, K0)                                                             \
  _Pragma("unroll")                                                                    \
  for (int p = 0; p < 2; p++) {                                                        \
    _Pragma("unroll")                                                                  \
    for (int c = wave; c < BM / 16; c += 4) {                                          \
      const u16* gp = gkA + (size_t)(m0 + c * 16 + lrow) * gkLD + (K0) + p * 32 + lcol; \
      gload16(gp, (char*)As + __builtin_amdgcn_readfirstlane((BU) * (BM * 128) + p * (BM * 64) + c * 1024)); \
    }                                                                                  \
    _Pragma("unroll")                                                                  \
    for (int c = wave; c < BN / 16; c += 4) {                                          \
      const u16* gp = gkB + (size_t)(n0 + c * 16 + lrow) * gkLD + (K0) + p * 32 + lcol; \
      gload16(gp, (char*)Bs + __builtin_amdgcn_readfirstlane((BU) * (BN * 128) + p * (BN * 64) + c * 1024)); \
    }                                                                                  \
  }

#define GK64_COMPUTE(BU)                                                               \
  _Pragma("unroll")                                                                    \
  for (int p = 0; p < 2; p++) {                                                        \
    bf16x8 af[WR], bfv[WC];                                                            \
    _Pragma("unroll")                                                                  \
    for (int i = 0; i < WR; i++)                                                       \
      af[i] = *(const bf16x8*)&As[(BU) * (BM * 64) + p * (BM * 32) + (wm + i * 16 + l16) * 32 + qsw]; \
    _Pragma("unroll")                                                                  \
    for (int j = 0; j < WC; j++)                                                       \
      bfv[j] = *(const bf16x8*)&Bs[(BU) * (BN * 64) + p * (BN * 32) + (wn + j * 16 + l16) * 32 + qsw]; \
    _Pragma("unroll")                                                                  \
    for (int i = 0; i < WR; i++)                                                       \
      _Pragma("unroll")                                                                \
      for (int j = 0; j < WC; j++)                                                     \
        acc[i][j] = __builtin_amdgcn_mfma_f32_16x16x32_bf16(af[i], bfv[j], acc[i][j], 0, 0, 0); \
  }

#define GEMM_KLOOP64(APTR, BPTR, KLEN, KLD)                                            \
  {                                                                                    \
    const u16* gkA = (APTR);                                                           \
    const u16* gkB = (BPTR);                                                           \
    const int gkLD = (KLD);                                                            \
    GK64_STAGE(0, 0)                                                                   \
    GK64_STAGE(1, 64)                                                                  \
    int gkcur = 0;                                                                     \
    for (int k0 = 0; k0 < (KLEN); k0 += 64) {                                          \
      if (k0 + 64 < (KLEN)) waitcnt_vm<WR + WC>();  /* older stage done; newer in flight */ \
      else waitcnt_vm<0>();                         /* last tile: drain */             \
      __builtin_amdgcn_s_barrier();                                                    \
      GK64_COMPUTE(gkcur)                                                              \
      __builtin_amdgcn_s_barrier();                 /* all reads of buf done */        \
      if (k0 + 128 < (KLEN)) { GK64_STAGE(gkcur, k0 + 128) }                           \
      gkcur ^= 1;                                                                      \
    }                                                                                  \
  }

// ---------- generic GEMM: MODE 0 bf16, MODE 1 relu->bf16, MODE 2 fp32 = v + resF ----------
template <int MODE, int WR, int WC>
__global__ __launch_bounds__(256, 4) void gemm_bt(
    const u16* __restrict__ A, const u16* __restrict__ Bt, const float* __restrict__ bias,
    u16* __restrict__ outB, float* __restrict__ outF, const float* __restrict__ resF,
    int M, int N, int K) {
  constexpr int BM = 2 * WR * 16;
  constexpr int BN = 2 * WC * 16;
  __shared__ u16 As[2 * BM * 32];
  __shared__ u16 Bs[2 * BN * 32];
  const int tid = threadIdx.x;
  const int wave = tid >> 6, lane = tid & 63, quad = lane >> 4, l16 = lane & 15;
  const int wm = (wave >> 1) * (WR * 16), wn = (wave & 1) * (WC * 16);
  int bx, by;
  xcd_swizzle(bx, by);
  const int m0 = by * BM, n0 = bx * BN;
  const int lrow = lane >> 2;
  const int lcol = (((lane & 3) ^ (lrow & 3)) * 8);   // pre-swizzled global col
  const int qsw = (quad ^ (l16 & 3)) * 8;             // swizzled read slot
  f32x4 acc[WR][WC] = {};
  GEMM_KLOOP(A, Bt, K, K)
#pragma unroll
  for (int i = 0; i < WR; i++)
#pragma unroll
    for (int j = 0; j < WC; j++) {
      int col = n0 + wn + j * 16 + l16;
      float bv = bias[col];
#pragma unroll
      for (int r = 0; r < 4; r++) {
        int row = m0 + wm + i * 16 + quad * 4 + r;
        size_t off = (size_t)row * N + col;
        float v = acc[i][j][r] + bv;
        if constexpr (MODE == 1) v = fmaxf(v, 0.f);
        if constexpr (MODE == 2) outF[off] = v + resF[off];
        else outB[off] = f2bf(v);
      }
    }
}

// ---------- fused QKV GEMM + RoPE (table-based): Bt = [wqT;wkT;wvT] ----------
// Q is additionally pre-scaled by EXP2SC (softmax exp2 scale folded in; Q buf
// is consumed only by flash_attn).
__global__ __launch_bounds__(256, 4) void gemm_qkv(
    const u16* __restrict__ A, const u16* __restrict__ Bt,
    const float* __restrict__ bq, const float* __restrict__ bk, const float* __restrict__ bv,
    const float* __restrict__ cosT, const float* __restrict__ sinT,
    u16* __restrict__ Qb, u16* __restrict__ Kb, u16* __restrict__ VT, int M, int K) {
  constexpr int WR = 4, WC = 4;
  constexpr int BM = 128, BN = 128;
  __shared__ u16 As[2 * BM * 32];
  __shared__ u16 Bs[2 * BN * 32];
  const int tid = threadIdx.x;
  const int wave = tid >> 6, lane = tid & 63, quad = lane >> 4, l16 = lane & 15;
  const int wm = (wave >> 1) * 64, wn = (wave & 1) * 64;
  int bx, by;
  xcd_swizzle(bx, by);
  const int m0 = by * BM, n0 = bx * BN;
  const int lrow = lane >> 2;
  const int lcol = (((lane & 3) ^ (lrow & 3)) * 8);
  const int qsw = (quad ^ (l16 & 3)) * 8;
  f32x4 acc[WR][WC] = {};
  GEMM_KLOOP(A, Bt, K, K)
  const int g = n0 >> 10;  // whole tile is one of Q/K/V (BN=128 divides 1024)
  if (g < 2) {
    // Q or K with fused RoPE via table. Pair (jp, jp+2): cols c0 and c0+32 (same head).
    u16* dst = (g == 0) ? Qb : Kb;
    const float* bias = (g == 0) ? bq : bk;
    const float scq = (g == 0) ? EXP2SC : 1.0f;
#pragma unroll
    for (int i = 0; i < WR; i++)
#pragma unroll
      for (int jp = 0; jp < 2; jp++) {
        int col0 = n0 + wn + jp * 16 + l16;
        int c0 = col0 & 1023;               // dk = c0&63 in [0,32)
        float bv0 = bias[c0], bv1 = bias[c0 + 32];
        int irot = jp * 16 + l16;           // rotation index (0..31)
        int row0 = m0 + wm + i * 16 + quad * 4;
#pragma unroll
        for (int r = 0; r < 4; r++) {
          int row = row0 + r;
          int s2 = row & 2047;
          float cs = cosT[s2 * 32 + irot];
          float sn = sinT[s2 * 32 + irot];
          float x0 = acc[i][jp][r] + bv0;
          float x1 = acc[i][jp + 2][r] + bv1;
          dst[(size_t)row * D_ + c0]      = f2bf((x0 * cs - x1 * sn) * scq);
          dst[(size_t)row * D_ + c0 + 32] = f2bf((x1 * cs + x0 * sn) * scq);
        }
      }
  } else {
#pragma unroll
    for (int i = 0; i < WR; i++)
#pragma unroll
      for (int j = 0; j < WC; j++) {
        int col = n0 + wn + j * 16 + l16;
        int c = col & 1023;
        float bvv = bv[c];
        int row0 = m0 + wm + i * 16 + quad * 4;
        int hh = c >> 6, dk = c & 63;
        int b = row0 >> 11, s2 = row0 & 2047;
        ushort4 pv;
        pv.x = f2bf(acc[i][j][0] + bvv);
        pv.y = f2bf(acc[i][j][1] + bvv);
        pv.z = f2bf(acc[i][j][2] + bvv);
        pv.w = f2bf(acc[i][j][3] + bvv);
        *(ushort4*)&VT[(((size_t)(b * H_ + hh)) * DK_ + dk) * S_ + s2] = pv;
      }
  }
}

// ---------- split-K GEMM, fp32 atomic-add epilogue (residual pre-loaded in outF) ----------
// R8-best config: BK=64 v3 loop (32 MFMAs/wave per barrier pair), z=2.
// z-fastest XCD swizzle keeps both atomic writers of a tile on one L2.
template <int WR, int WC>
__global__ __launch_bounds__(256) void gemm_splitk(
    const u16* __restrict__ A, const u16* __restrict__ Bt, const float* __restrict__ bias,
    float* outF, int M, int N, int Kslice, int Kld) {
  constexpr int BM = 2 * WR * 16;
  constexpr int BN = 2 * WC * 16;
  __shared__ u16 As[2 * BM * 64];
  __shared__ u16 Bs[2 * BN * 64];
  const int tid = threadIdx.x;
  const int wave = tid >> 6, lane = tid & 63, quad = lane >> 4, l16 = lane & 15;
  const int wm = (wave >> 1) * (WR * 16), wn = (wave & 1) * (WC * 16);
  int bx, by, bz;
  xcd_swizzle3(bx, by, bz);
  const int m0 = by * BM, n0 = bx * BN;
  const int lrow = lane >> 2;
  const int lcol = (((lane & 3) ^ (lrow & 3)) * 8);
  const int qsw = (quad ^ (l16 & 3)) * 8;
  const u16* Ao = A + (size_t)bz * Kslice;
  const u16* Bo = Bt + (size_t)bz * Kslice;
  f32x4 acc[WR][WC] = {};
  GEMM_KLOOP64(Ao, Bo, Kslice, Kld)
  const bool addb = (bz == 0);
#pragma unroll
  for (int i = 0; i < WR; i++)
#pragma unroll
    for (int j = 0; j < WC; j++) {
      int col = n0 + wn + j * 16 + l16;
      float bv = addb ? bias[col] : 0.f;
#pragma unroll
      for (int r = 0; r < 4; r++) {
        int row = m0 + wm + i * 16 + quad * 4 + r;
        unsafeAtomicAdd(&outF[(size_t)row * N + col], acc[i][j][r] + bv);
      }
    }
}

// ---------- flash attention v5 ----------
// 128 q-rows/block (4 waves x 32 q), 64-key tiles double-buffered with the
// T4 counted-vmcnt schedule. 32KB LDS -> 4 blocks/CU = 4 waves/SIMD.
// Swapped QK^T; P in-register (cvt_pk + permlane); raw v_exp_f32 (exp2r);
// softmax denominator via MFMA ones-trick.
__device__ __forceinline__ void softmax_pack(f32x4 s0, f32x4 s1, f32x4 s2, f32x4 s3,
                                             bf16x8& pf0, bf16x8& pf1) {
  f32x4 p0, p1, p2, p3;
#pragma unroll
  for (int r = 0; r < 4; r++) {
    p0[r] = exp2r(s0[r]);
    p1[r] = exp2r(s1[r]);
    p2[r] = exp2r(s2[r]);
    p3[r] = exp2r(s3[r]);
  }
  unsigned int X0 = cvtpk(p0[0], p0[1]), X1 = cvtpk(p0[2], p0[3]);
  unsigned int Y0 = cvtpk(p1[0], p1[1]), Y1 = cvtpk(p1[2], p1[3]);
  unsigned int Z0 = cvtpk(p2[0], p2[1]), Z1 = cvtpk(p2[2], p2[3]);
  unsigned int W0 = cvtpk(p3[0], p3[1]), W1 = cvtpk(p3[2], p3[3]);
  // redistribute: after (swap32; swap16), first reg = dword j, second = dword j+2
  plswap32(X0, Y0); plswap16(X0, Y0);
  plswap32(X1, Y1); plswap16(X1, Y1);
  plswap32(Z0, W0); plswap16(Z0, W0);
  plswap32(Z1, W1); plswap16(Z1, W1);
  u32x4 lo = {X0, X1, Y0, Y1};
  u32x4 hi = {Z0, Z1, W0, W1};
  pf0 = __builtin_bit_cast(bf16x8, lo);
  pf1 = __builtin_bit_cast(bf16x8, hi);
}

__global__ __launch_bounds__(256, 4) void flash_attn(u16* __restrict__ Q,
                                                     const u16* __restrict__ Kg,
                                                     const u16* __restrict__ VT) {
  const int bh = blockIdx.y;
  const int b = bh >> 4, h = bh & 15;
  const int q0 = blockIdx.x * 128;
  const int tid = threadIdx.x;
  const int wave = tid >> 6, lane = tid & 63, quad = lane >> 4, l16 = lane & 15;
  const size_t base = (size_t)b * S_ * D_ + h * DK_;
  const size_t vbase = (size_t)bh * DK_ * S_;

  __shared__ u16 Ks[2][4096];   // per buf [64key][64dk]: byte = key*128 + (colb ^ ((key&7)<<4))
  __shared__ u16 Vts[2][4096];  // per buf [64dk][64key]: byte = dk*128  + (colb ^ ((dk&7)<<4))

  // staging: wave w covers rows w*16..w*16+15 (8 lanes/row, 2 gloads of 8 rows)
  const int srow8 = lane >> 3;                        // 0..7
  const int scol = ((lane & 7) ^ srow8) * 8;          // pre-swizzled u16 col
  const int kkey = wave * 16 + srow8;                 // +c*8 ; kkey&7 == srow8
  const u16* kp0 = Kg + base + (size_t)kkey * D_ + scol;
  const int vdk = wave * 16 + srow8;                  // +c*8 ; vdk&7 == srow8
  const u16* vp0 = VT + vbase + (size_t)vdk * S_ + scol;

#define FA_STAGE(BU, KT)                                                               \
  _Pragma("unroll")                                                                    \
  for (int c = 0; c < 2; c++) {                                                        \
    gload16(kp0 + (size_t)((KT) + c * 8) * D_,                                         \
            (char*)Ks + __builtin_amdgcn_readfirstlane((BU) * 8192 + wave * 2048 + c * 1024)); \
    gload16(vp0 + (size_t)(c * 8) * S_ + (KT),                                         \
            (char*)Vts + __builtin_amdgcn_readfirstlane((BU) * 8192 + wave * 2048 + c * 1024)); \
  }

  FA_STAGE(0, 0)
  FA_STAGE(1, 64)

  // Q fragments: qset a = rows wave*32+l16, qset b = +16; cols quad*8 (+32)
  const size_t qoffA = base + (size_t)(q0 + wave * 32 + l16) * D_ + quad * 8;
  const size_t qoffB = qoffA + (size_t)16 * D_;
  bf16x8 qa0 = *(const bf16x8*)(Q + qoffA);
  bf16x8 qa1 = *(const bf16x8*)(Q + qoffA + 32);
  bf16x8 qb0 = *(const bf16x8*)(Q + qoffB);
  bf16x8 qb1 = *(const bf16x8*)(Q + qoffB + 32);

  f32x4 oa[4] = {}, ob[4] = {};
  f32x4 lsa_acc = {}, lsb_acc = {};
  const u32x4 onesu = {0x3F803F80u, 0x3F803F80u, 0x3F803F80u, 0x3F803F80u};
  const bf16x8 ones = __builtin_bit_cast(bf16x8, onesu);
  const int sw = (l16 & 7) << 4;

#define FA_TILE(BU)                                                                    \
  {                                                                                    \
    const char* KsB = (const char*)Ks + (BU) * 8192;                                   \
    const char* VtsB = (const char*)Vts + (BU) * 8192;                                 \
    f32x4 sa[4] = {}, sb[4] = {};                                                      \
    __builtin_amdgcn_s_setprio(1);                                                     \
    _Pragma("unroll")                                                                  \
    for (int nt = 0; nt < 4; nt++) {                                                   \
      const char* krow = KsB + (nt * 16 + l16) * 128;                                  \
      bf16x8 k0 = *(const bf16x8*)(krow + ((quad * 16) ^ sw));                         \
      bf16x8 k1 = *(const bf16x8*)(krow + ((64 + quad * 16) ^ sw));                    \
      sa[nt] = __builtin_amdgcn_mfma_f32_16x16x32_bf16(k0, qa0, sa[nt], 0, 0, 0);      \
      sa[nt] = __builtin_amdgcn_mfma_f32_16x16x32_bf16(k1, qa1, sa[nt], 0, 0, 0);      \
      sb[nt] = __builtin_amdgcn_mfma_f32_16x16x32_bf16(k0, qb0, sb[nt], 0, 0, 0);      \
      sb[nt] = __builtin_amdgcn_mfma_f32_16x16x32_bf16(k1, qb1, sb[nt], 0, 0, 0);      \
    }                                                                                  \
    __builtin_amdgcn_s_setprio(0);                                                     \
    bf16x8 pa0, pa1, pb0, pb1;                                                         \
    softmax_pack(sa[0], sa[1], sa[2], sa[3], pa0, pa1);                                \
    softmax_pack(sb[0], sb[1], sb[2], sb[3], pb0, pb1);                                \
    __builtin_amdgcn_s_setprio(1);                                                     \
    lsa_acc = __builtin_amdgcn_mfma_f32_16x16x32_bf16(pa0, ones, lsa_acc, 0, 0, 0);    \
    lsa_acc = __builtin_amdgcn_mfma_f32_16x16x32_bf16(pa1, ones, lsa_acc, 0, 0, 0);    \
    lsb_acc = __builtin_amdgcn_mfma_f32_16x16x32_bf16(pb0, ones, lsb_acc, 0, 0, 0);    \
    lsb_acc = __builtin_amdgcn_mfma_f32_16x16x32_bf16(pb1, ones, lsb_acc, 0, 0, 0);    \
    _Pragma("unroll")                                                                  \
    for (int nt = 0; nt < 4; nt++) {                                                   \
      const char* vrow = VtsB + (nt * 16 + l16) * 128;                                 \
      bf16x8 v0 = *(const bf16x8*)(vrow + ((quad * 16) ^ sw));                         \
      bf16x8 v1 = *(const bf16x8*)(vrow + ((64 + quad * 16) ^ sw));                    \
      oa[nt] = __builtin_amdgcn_mfma_f32_16x16x32_bf16(pa0, v0, oa[nt], 0, 0, 0);      \
      oa[nt] = __builtin_amdgcn_mfma_f32_16x16x32_bf16(pa1, v1, oa[nt], 0, 0, 0);      \
      ob[nt] = __builtin_amdgcn_mfma_f32_16x16x32_bf16(pb0, v0, ob[nt], 0, 0, 0);      \
      ob[nt] = __builtin_amdgcn_mfma_f32_16x16x32_bf16(pb1, v1, ob[nt], 0, 0, 0);      \
    }                                                                                  \
    __builtin_amdgcn_s_setprio(0);                                                     \
  }

  // T4 schedule: vmcnt(4) retires only the older stage; the newer one stays
  // in flight across both barriers, hidden under a full tile of MFMA+VALU.
  int cur = 0;
  for (int kt = 0; kt < S_; kt += 64) {
    if (kt + 64 < S_) waitcnt_vm<4>();
    else waitcnt_vm<0>();
    __builtin_amdgcn_s_barrier();
    FA_TILE(cur)
    __builtin_amdgcn_s_barrier();
    if (kt + 128 < S_) { FA_STAGE(cur, kt + 128) }
    cur ^= 1;
  }
#undef FA_STAGE
#undef FA_TILE

  // lsX_acc[r] holds sum_k P[q][k] for q = quad*4+r on every l16 lane --
  // exactly the rows oa/ob[nt][r] cover; no cross-lane reduction needed.
#pragma unroll
  for (int r = 0; r < 4; r++) {
    float inva = 1.0f / lsa_acc[r];
    float invb = 1.0f / lsb_acc[r];
    const size_t aoff = base + (size_t)(q0 + wave * 32 + quad * 4 + r) * D_;
    const size_t boff = aoff + (size_t)16 * D_;
#pragma unroll
    for (int nt = 0; nt < 4; nt++) {
      Q[aoff + nt * 16 + l16] = f2bf(oa[nt][r] * inva);
      Q[boff + nt * 16 + l16] = f2bf(ob[nt][r] * invb);
    }
  }
}

extern "C" void kernel_launch(void* const* d_in, const int* in_sizes, int n_in,
                              void* d_out, int out_size, void* d_ws, size_t ws_size,
                              hipStream_t stream) {
  const float* x  = (const float*)d_in[0];
  const float* wq = (const float*)d_in[1];
  const float* bq = (const float*)d_in[2];
  const float* wk = (const float*)d_in[3];
  const float* bk = (const float*)d_in[4];
  const float* wv = (const float*)d_in[5];
  const float* bv = (const float*)d_in[6];
  const float* wo = (const float*)d_in[7];
  const float* bo = (const float*)d_in[8];
  const float* w1 = (const float*)d_in[9];
  const float* b1 = (const float*)d_in[10];
  const float* w2 = (const float*)d_in[11];
  const float* b2 = (const float*)d_in[12];
  const float* g1 = (const float*)d_in[13];
  const float* g2 = (const float*)d_in[14];

  // ---- workspace ----
  // [0,6):  wqT|wkT|wvT -> w2T [0,2) after O-proj
  // [6,8):  woT
  // [8,16): h -> h2
  // [16,24): Qb -> O in-place -> w1T after O-proj
  // [24,32): Kb -> f1
  // [32,40): tables (512KB, dead after gemm_qkv) -> f1
  // f1: [24,56) if ws_size >= 57MB (single-dispatch FFN), else [24,40) halves
  // d_out: VT bf16 [0,8MB) during attention -> x2 fp32 (16MB) -> final
  char* ws = (char*)d_ws;
  const size_t MB = 1024 * 1024;
  u16* qkvT = (u16*)(ws + 0 * MB);
  u16* woT  = (u16*)(ws + 6 * MB);
  u16* h    = (u16*)(ws + 8 * MB);
  u16* Qb   = (u16*)(ws + 16 * MB);
  u16* Kb   = (u16*)(ws + 24 * MB);
  float* cosT = (float*)(ws + 32 * MB);
  float* sinT = (float*)(ws + 32 * MB + 256 * 1024);
  u16* w2T  = (u16*)(ws + 0 * MB);
  u16* w1T  = (u16*)(ws + 16 * MB);
  u16* f1   = (u16*)(ws + 24 * MB);
  u16* h2   = h;
  u16* Ob   = Qb;
  u16* VT   = (u16*)d_out;
  float* x2 = (float*)d_out;
  const bool bigffn = (ws_size >= 57 * MB);

  const int MS = B_ * S_;  // 4096
  prep_qkvo<<<4096 + S_ * 32 / 256, 256, 0, stream>>>(wq, wk, wv, wo, qkvT, woT, cosT, sinT);
  rmsnorm_k<<<MS, 256, 0, stream>>>(x, g1, h);
  gemm_qkv<<<dim3(3 * D_ / 128, MS / 128), 256, 0, stream>>>(h, qkvT, bq, bk, bv, cosT, sinT, Qb, Kb, VT, MS, D_);
  flash_attn<<<dim3(S_ / 128, B_ * H_), 256, 0, stream>>>(Qb, Kb, VT);
  // x2 = O @ wo + bo + x -> d_out fp32 (VT dead); 128x64 tile -> 512 blocks
  gemm_bt<2, 4, 2><<<dim3(D_ / 64, MS / 128), 256, 0, stream>>>(Ob, woT, bo, nullptr, x2, x, MS, D_, D_);

  prep_w12<<<8192, 256, 0, stream>>>(w1, w2, w1T, w2T);  // over dead O / dead wq,wk
  rmsnorm_k<<<MS, 256, 0, stream>>>(x2, g2, h2);
  if (bigffn) {
    // single-dispatch FFN: f1 = 4096x4096 bf16 (32MB) at [24,56)
    // split-K z=2 (Kslice 2048): R8-best; z-local swizzle for atomic locality.
    gemm_bt<1, 4, 4><<<dim3(DFF_ / 128, MS / 128), 256, 0, stream>>>(h2, w1T, b1, f1, nullptr, nullptr, MS, DFF_, D_);
    gemm_splitk<4, 4><<<dim3(D_ / 128, MS / 128, 2), 256, 0, stream>>>(f1, w2T, b2, x2, MS, D_, 2048, DFF_);
  } else {
    for (int i = 0; i < 2; i++) {
      const u16* h2h = h2 + (size_t)i * 2048 * D_;
      float* x2h = x2 + (size_t)i * 2048 * D_;
      gemm_bt<1, 4, 4><<<dim3(DFF_ / 128, 2048 / 128), 256, 0, stream>>>(h2h, w1T, b1, f1, nullptr, nullptr, 2048, DFF_, D_);
      gemm_splitk<4, 4><<<dim3(D_ / 128, 2048 / 128, 4), 256, 0, stream>>>(f1, w2T, b2, x2h, 2048, D_, 1024, DFF_);
    }
  }
  (void)in_sizes; (void)n_in; (void)out_size;
}